// Round 1
// baseline (864.079 us; speedup 1.0000x reference)
//
#include <hip/hip_runtime.h>
#include <math.h>

#define LQ 1024
#define DH 1024
#define NH 16
#define DKH 64

// ---------------- physics precompute: retention, coeff, gate sigmoid ----------------
__global__ __launch_bounds__(256) void physics_kernel(
    const float* __restrict__ W_LTM, const float* __restrict__ V_gs, const float* __restrict__ V_T0,
    const float* __restrict__ beta_tau, const float* __restrict__ beta_gm, const float* __restrict__ C_ch,
    const float* __restrict__ gamma_, const float* __restrict__ alpha_ppd, const float* __restrict__ IC_thr,
    const float* __restrict__ gate, float* __restrict__ ret, float* __restrict__ co, float* __restrict__ g_out) {
  int idx = blockIdx.x * 256 + threadIdx.x;      // 65536 = H*DK*DK
  int h = idx >> 12;
  float w = W_LTM[idx];
  float veff = V_gs[h] - V_T0[h] + w;
  float sp = fmaxf(veff, 0.f) + log1pf(expf(-fabsf(veff)));   // stable softplus
  float gch = beta_tau[h] * sp;
  float retv = expf(-gch / C_ch[h]);
  float sig = 1.f / (1.f + expf(-veff));
  float G = beta_gm[h] * sp * sig;
  float sm = tanhf(alpha_ppd[0] * (gch - IC_thr[0]));
  ret[idx] = retv;
  co[idx] = gamma_[h] * sm * G;
  if (idx < NH) g_out[idx] = 1.f / (1.f + expf(-gate[idx]));
}

// ---------------- tiled fp32 GEMM: C[M,N] = A[M,K] @ B[K,N]; MIX fuses gating ----------------
template <bool MIX>
__global__ __launch_bounds__(256) void gemm_kernel(
    const float* __restrict__ A, const float* __restrict__ Bm, float* __restrict__ C,
    int M, int N, int K, const float* __restrict__ A2, const float* __restrict__ gates) {
  __shared__ float As[16][132];
  __shared__ float Bs[16][132];
  const int tid = threadIdx.x;
  const int tx = tid & 15, ty = tid >> 4;
  const int row0 = blockIdx.y * 128, col0 = blockIdx.x * 128;
  float acc[8][8];
#pragma unroll
  for (int i = 0; i < 8; i++)
#pragma unroll
    for (int j = 0; j < 8; j++) acc[i][j] = 0.f;

  for (int k0 = 0; k0 < K; k0 += 16) {
#pragma unroll
    for (int i = 0; i < 8; i++) {            // A tile 128x16
      int idx = tid + 256 * i;
      int r = idx >> 4, c = idx & 15;
      float a = A[(size_t)(row0 + r) * K + k0 + c];
      if (MIX) {
        int kk = k0 + c;
        float g = gates[kk >> 6];
        a = g * a + (1.f - g) * A2[(size_t)(row0 + r) * K + kk];
      }
      As[c][r] = a;
    }
#pragma unroll
    for (int i = 0; i < 8; i++) {            // B tile 16x128
      int idx = tid + 256 * i;
      int r = idx >> 7, c = idx & 127;
      Bs[r][c] = Bm[(size_t)(k0 + r) * N + col0 + c];
    }
    __syncthreads();
#pragma unroll
    for (int kk = 0; kk < 16; kk++) {
      float a[8], b[8];
#pragma unroll
      for (int i = 0; i < 8; i++) a[i] = As[kk][ty * 8 + i];
#pragma unroll
      for (int i = 0; i < 8; i++) b[i] = Bs[kk][tx * 8 + i];
#pragma unroll
      for (int i = 0; i < 8; i++)
#pragma unroll
        for (int j = 0; j < 8; j++) acc[i][j] = fmaf(a[i], b[j], acc[i][j]);
    }
    __syncthreads();
  }
#pragma unroll
  for (int i = 0; i < 8; i++) {
    float* cp = &C[(size_t)(row0 + ty * 8 + i) * N + col0 + tx * 8];
    float4 c0 = {acc[i][0], acc[i][1], acc[i][2], acc[i][3]};
    float4 c1 = {acc[i][4], acc[i][5], acc[i][6], acc[i][7]};
    *(float4*)cp = c0;
    *(float4*)(cp + 4) = c1;
  }
}

// ---------------- LayerNorm of k over DK (no affine) ----------------
__global__ __launch_bounds__(256) void ln_kernel(const float* __restrict__ qkv, float* __restrict__ kn) {
  int gid = blockIdx.x * 4 + (threadIdx.x >> 6);  // row in [0, B*L*H)
  int lane = threadIdx.x & 63;
  int bl = gid >> 4, h = gid & 15;
  float v = qkv[(size_t)(bl * 3 + 1) * DH + h * DKH + lane];
  float s = v;
#pragma unroll
  for (int off = 1; off < 64; off <<= 1) s += __shfl_xor(s, off);
  float mu = s * (1.f / 64.f);
  float d = v - mu;
  float s2 = d * d;
#pragma unroll
  for (int off = 1; off < 64; off <<= 1) s2 += __shfl_xor(s2, off);
  float var = s2 * (1.f / 64.f);
  kn[(size_t)gid * 64 + lane] = d * rsqrtf(var + 1e-5f);
}

// ---------------- causal flash attention (fp32), raw k ----------------
__global__ __launch_bounds__(256) void attn_kernel(const float* __restrict__ qkv, float* __restrict__ so) {
  const int it = blockIdx.x, h = blockIdx.y, bb = blockIdx.z;
  const int tid = threadIdx.x;
  const int r = tid >> 2, grp = tid & 3;
  __shared__ float Qs[64][68];
  __shared__ float Ks[32][68];
  __shared__ float Vs[32][68];
  __shared__ float Ps[64][36];
  const int i0 = it * 64;
#pragma unroll
  for (int i = 0; i < 16; i++) {
    int idx = tid + 256 * i;
    int rr = idx >> 6, e = idx & 63;
    Qs[rr][e] = qkv[((size_t)(bb * LQ + i0 + rr) * 3 + 0) * DH + h * DKH + e];
  }
  float m = -1e30f, l = 0.f;
  float o[16];
#pragma unroll
  for (int i = 0; i < 16; i++) o[i] = 0.f;
  __syncthreads();
  const int ntiles = (it + 1) * 2;
  for (int jt = 0; jt < ntiles; jt++) {
    const int j0 = jt * 32;
#pragma unroll
    for (int i = 0; i < 8; i++) {
      int idx = tid + 256 * i;
      int kk = idx >> 6, e = idx & 63;
      Ks[kk][e] = qkv[((size_t)(bb * LQ + j0 + kk) * 3 + 1) * DH + h * DKH + e];
      Vs[kk][e] = qkv[((size_t)(bb * LQ + j0 + kk) * 3 + 2) * DH + h * DKH + e];
    }
    __syncthreads();
    float acc[8];
#pragma unroll
    for (int mm = 0; mm < 8; mm++) acc[mm] = 0.f;
#pragma unroll
    for (int e4 = 0; e4 < 16; e4++) {
      float4 qv = *(const float4*)&Qs[r][e4 * 4];
#pragma unroll
      for (int mm = 0; mm < 8; mm++) {
        float4 kv = *(const float4*)&Ks[mm * 4 + grp][e4 * 4];
        acc[mm] = fmaf(qv.x, kv.x, acc[mm]);
        acc[mm] = fmaf(qv.y, kv.y, acc[mm]);
        acc[mm] = fmaf(qv.z, kv.z, acc[mm]);
        acc[mm] = fmaf(qv.w, kv.w, acc[mm]);
      }
    }
    float tmax = -1e30f;
#pragma unroll
    for (int mm = 0; mm < 8; mm++) {
      int k = mm * 4 + grp;
      acc[mm] *= 0.125f;
      if (j0 + k > i0 + r) acc[mm] = -1e30f;
      tmax = fmaxf(tmax, acc[mm]);
    }
    tmax = fmaxf(tmax, __shfl_xor(tmax, 1));
    tmax = fmaxf(tmax, __shfl_xor(tmax, 2));
    float mnew = fmaxf(m, tmax);
    float alpha = expf(m - mnew);
    float tsum = 0.f;
#pragma unroll
    for (int mm = 0; mm < 8; mm++) {
      float pv = expf(acc[mm] - mnew);
      Ps[r][mm * 4 + grp] = pv;
      tsum += pv;
    }
    tsum += __shfl_xor(tsum, 1);
    tsum += __shfl_xor(tsum, 2);
    l = l * alpha + tsum;
    m = mnew;
#pragma unroll
    for (int i = 0; i < 16; i++) o[i] *= alpha;
    // Ps rows are produced by the same wave that consumes them -> no barrier needed
#pragma unroll
    for (int k = 0; k < 32; k++) {
      float pk = Ps[r][k];
#pragma unroll
      for (int i = 0; i < 16; i++) o[i] = fmaf(pk, Vs[k][grp * 16 + i], o[i]);
    }
    __syncthreads();
  }
  float inv = 1.f / l;
  float* op = &so[(size_t)(bb * LQ + i0 + r) * DH + h * DKH + grp * 16];
#pragma unroll
  for (int i4 = 0; i4 < 4; i4++) {
    float4 c = {o[i4 * 4] * inv, o[i4 * 4 + 1] * inv, o[i4 * 4 + 2] * inv, o[i4 * 4 + 3] * inv};
    *(float4*)(op + i4 * 4) = c;
  }
}

// ---------------- STP scan: 2048 independent row-sequences; 64 blocks x 32 rows ----------------
__global__ __launch_bounds__(256) void scan_kernel(
    const float* __restrict__ qkv, const float* __restrict__ kn, const float* __restrict__ W_LTM,
    const float* __restrict__ ret_g, const float* __restrict__ co_g, float* __restrict__ stp) {
  const int bh = blockIdx.x >> 1;
  const int half = blockIdx.x & 1;
  const int bb = bh >> 4, h = bh & 15;
  const int tid = threadIdx.x;
  const int dl = tid >> 3;   // 0..31 local row
  const int j = tid & 7;     // 8 col-groups of 8
  const int d = half * 32 + dl;
  float F[8], R[8], Cc[8], W[8];
  const int base = h * 4096 + d * 64 + j * 8;
#pragma unroll
  for (int i = 0; i < 8; i++) {
    F[i] = 0.f;
    R[i] = ret_g[base + i];
    Cc[i] = co_g[base + i];
    W[i] = W_LTM[base + i];
  }
  __shared__ float qb[2][8][64], kb[2][8][64], vb[2][8][64];

  float ld[6];
  // chunk 0 load
#pragma unroll
  for (int i = 0; i < 6; i++) {
    int idx = tid + 256 * i;
    int which = idx >> 9, rem = idx & 511, s = rem >> 6, e = rem & 63;
    int t = s;
    if (which == 0)      ld[i] = qkv[((size_t)(bb * LQ + t) * 3 + 0) * DH + h * DKH + e];
    else if (which == 1) ld[i] = kn[((size_t)(bb * LQ + t) * NH + h) * DKH + e];
    else                 ld[i] = qkv[((size_t)(bb * LQ + t) * 3 + 2) * DH + h * DKH + e];
  }
#pragma unroll
  for (int i = 0; i < 6; i++) {
    int idx = tid + 256 * i;
    int which = idx >> 9, rem = idx & 511, s = rem >> 6, e = rem & 63;
    if (which == 0) qb[0][s][e] = ld[i];
    else if (which == 1) kb[0][s][e] = ld[i];
    else vb[0][s][e] = ld[i];
  }
  __syncthreads();

  for (int c = 0; c < 128; c++) {
    const int p = c & 1;
    float l2[6];
    if (c < 127) {
      int t0 = (c + 1) * 8;
#pragma unroll
      for (int i = 0; i < 6; i++) {
        int idx = tid + 256 * i;
        int which = idx >> 9, rem = idx & 511, s = rem >> 6, e = rem & 63;
        int t = t0 + s;
        if (which == 0)      l2[i] = qkv[((size_t)(bb * LQ + t) * 3 + 0) * DH + h * DKH + e];
        else if (which == 1) l2[i] = kn[((size_t)(bb * LQ + t) * NH + h) * DKH + e];
        else                 l2[i] = qkv[((size_t)(bb * LQ + t) * 3 + 2) * DH + h * DKH + e];
      }
    }
#pragma unroll
    for (int s = 0; s < 8; s++) {
      float vd = vb[p][s][d];
      float yp = 0.f;
#pragma unroll
      for (int i = 0; i < 8; i++) {
        float ke = kb[p][s][j * 8 + i];
        F[i] = fmaf(Cc[i], vd * ke, R[i] * F[i]);
        yp = fmaf(W[i] + F[i], qb[p][s][j * 8 + i], yp);
      }
      yp += __shfl_xor(yp, 1);
      yp += __shfl_xor(yp, 2);
      yp += __shfl_xor(yp, 4);
      if (j == 0) stp[((size_t)(bb * LQ + c * 8 + s) * NH + h) * DKH + d] = yp;
    }
    if (c < 127) {
      const int pn = p ^ 1;
#pragma unroll
      for (int i = 0; i < 6; i++) {
        int idx = tid + 256 * i;
        int which = idx >> 9, rem = idx & 511, s = rem >> 6, e = rem & 63;
        if (which == 0) qb[pn][s][e] = l2[i];
        else if (which == 1) kb[pn][s][e] = l2[i];
        else vb[pn][s][e] = l2[i];
      }
    }
    __syncthreads();
  }
}

extern "C" void kernel_launch(void* const* d_in, const int* in_sizes, int n_in,
                              void* d_out, int out_size, void* d_ws, size_t ws_size,
                              hipStream_t stream) {
  (void)in_sizes; (void)n_in; (void)out_size; (void)ws_size;
  const float* x        = (const float*)d_in[0];
  const float* W_qkv    = (const float*)d_in[1];
  const float* W_o      = (const float*)d_in[2];
  const float* W_LTM    = (const float*)d_in[3];
  const float* V_gs     = (const float*)d_in[4];
  const float* V_T0     = (const float*)d_in[5];
  const float* beta_tau = (const float*)d_in[6];
  const float* beta_gm  = (const float*)d_in[7];
  const float* C_ch     = (const float*)d_in[8];
  const float* gamma_   = (const float*)d_in[9];
  const float* alpha_p  = (const float*)d_in[10];
  const float* IC_thr   = (const float*)d_in[11];
  const float* gate     = (const float*)d_in[12];

  float* ws  = (float*)d_ws;
  float* qkv = ws;                    // 2*1024*3072 = 6291456
  float* kn  = qkv + 6291456;         // 2097152
  float* so  = kn + 2097152;          // 2097152
  float* stp = so + 2097152;          // 2097152
  float* ret = stp + 2097152;         // 65536
  float* co  = ret + 65536;           // 65536
  float* g   = co + 65536;            // 16
  float* out = (float*)d_out;

  physics_kernel<<<256, 256, 0, stream>>>(W_LTM, V_gs, V_T0, beta_tau, beta_gm, C_ch,
                                          gamma_, alpha_p, IC_thr, gate, ret, co, g);
  gemm_kernel<false><<<dim3(24, 16), 256, 0, stream>>>(x, W_qkv, qkv, 2048, 3072, 1024, nullptr, nullptr);
  ln_kernel<<<8192, 256, 0, stream>>>(qkv, kn);
  attn_kernel<<<dim3(16, 16, 2), 256, 0, stream>>>(qkv, so);
  scan_kernel<<<64, 256, 0, stream>>>(qkv, kn, W_LTM, ret, co, stp);
  gemm_kernel<true><<<dim3(8, 16), 256, 0, stream>>>(so, W_o, out, 2048, 1024, 1024, stp, g);
}

// Round 2
// 588.575 us; speedup vs baseline: 1.4681x; 1.4681x over previous
//
#include <hip/hip_runtime.h>
#include <hip/hip_bf16.h>
#include <math.h>

#define LQ 1024
#define DH 1024
#define NH 16
#define DKH 64

typedef __bf16 bf16x8 __attribute__((ext_vector_type(8)));
typedef float f32x4 __attribute__((ext_vector_type(4)));
typedef const unsigned int __attribute__((address_space(1)))* gas1_t;
typedef unsigned int __attribute__((address_space(3)))* las3_t;

// ---------------- physics precompute: retention, coeff, gate sigmoid ----------------
__global__ __launch_bounds__(256) void physics_kernel(
    const float* __restrict__ W_LTM, const float* __restrict__ V_gs, const float* __restrict__ V_T0,
    const float* __restrict__ beta_tau, const float* __restrict__ beta_gm, const float* __restrict__ C_ch,
    const float* __restrict__ gamma_, const float* __restrict__ alpha_ppd, const float* __restrict__ IC_thr,
    const float* __restrict__ gate, float* __restrict__ ret, float* __restrict__ co, float* __restrict__ g_out) {
  int idx = blockIdx.x * 256 + threadIdx.x;      // 65536 = H*DK*DK
  int h = idx >> 12;
  float w = W_LTM[idx];
  float veff = V_gs[h] - V_T0[h] + w;
  float sp = fmaxf(veff, 0.f) + log1pf(expf(-fabsf(veff)));   // stable softplus
  float gch = beta_tau[h] * sp;
  float retv = expf(-gch / C_ch[h]);
  float sig = 1.f / (1.f + expf(-veff));
  float G = beta_gm[h] * sp * sig;
  float sm = tanhf(alpha_ppd[0] * (gch - IC_thr[0]));
  ret[idx] = retv;
  co[idx] = gamma_[h] * sm * G;
  if (idx < NH) g_out[idx] = 1.f / (1.f + expf(-gate[idx]));
}

// ---------------- fp32 -> bf16 elementwise (x) ----------------
__global__ __launch_bounds__(256) void cvt_kernel(const float* __restrict__ in, __hip_bfloat16* __restrict__ out) {
  size_t i = (size_t)(blockIdx.x * 256 + threadIdx.x) * 4;
  float4 v = *(const float4*)(in + i);
  __hip_bfloat16 t[4] = {__float2bfloat16(v.x), __float2bfloat16(v.y),
                         __float2bfloat16(v.z), __float2bfloat16(v.w)};
  *(uint2*)(out + i) = *(uint2*)t;
}

// ---------------- fp32 [K][N] -> bf16 [N][K] transpose-convert ----------------
__global__ __launch_bounds__(256) void tcvt_kernel(const float* __restrict__ W, __hip_bfloat16* __restrict__ Wt,
                                                   int K, int N) {
  __shared__ float t[32][33];
  int n0 = blockIdx.x * 32, k0 = blockIdx.y * 32;
  int r = threadIdx.x >> 5, c = threadIdx.x & 31;
#pragma unroll
  for (int i = 0; i < 4; i++) t[r + 8 * i][c] = W[(size_t)(k0 + r + 8 * i) * N + n0 + c];
  __syncthreads();
#pragma unroll
  for (int i = 0; i < 4; i++)
    Wt[(size_t)(n0 + r + 8 * i) * K + k0 + c] = __float2bfloat16(t[c][r + 8 * i]);
}

// ---------------- gate mix -> bf16 ----------------
__global__ __launch_bounds__(256) void mix_kernel(const float* __restrict__ so, const float* __restrict__ stp,
                                                  const float* __restrict__ g, __hip_bfloat16* __restrict__ out) {
  size_t base = (size_t)(blockIdx.x * 256 + threadIdx.x) * 4;
  float gv = g[(base >> 6) & 15];
  float4 a = *(const float4*)(so + base);
  float4 b = *(const float4*)(stp + base);
  __hip_bfloat16 t[4] = {__float2bfloat16(gv * a.x + (1.f - gv) * b.x),
                         __float2bfloat16(gv * a.y + (1.f - gv) * b.y),
                         __float2bfloat16(gv * a.z + (1.f - gv) * b.z),
                         __float2bfloat16(gv * a.w + (1.f - gv) * b.w)};
  *(uint2*)(out + base) = *(uint2*)t;
}

// ---------------- bf16 MFMA GEMM (m97 structure): C[M,N] = A[M,K] * Bt[N,K]^T ----------------
__global__ __launch_bounds__(256) void gemm_bt_kernel(
    const __hip_bfloat16* __restrict__ A, const __hip_bfloat16* __restrict__ Bt,
    float* __restrict__ C, int M, int N, int K) {
  __shared__ unsigned short As[128 * 32];
  __shared__ unsigned short Bs[128 * 32];
  const int tid = threadIdx.x;
  const int w = tid >> 6, lane = tid & 63;
  const int quad = lane >> 4, l16 = lane & 15;
  const int wm = w & 1, wn = w >> 1;
  const int row0 = blockIdx.y * 128, col0 = blockIdx.x * 128;
  const int sr = lane >> 2;          // 0..15: row within 16-row segment
  const int sk = (lane & 3) * 8;     // k element offset (8 bf16 = 16B)
  f32x4 acc[4][4];
#pragma unroll
  for (int i = 0; i < 4; i++)
#pragma unroll
    for (int j = 0; j < 4; j++) acc[i][j] = (f32x4){0.f, 0.f, 0.f, 0.f};

  for (int k0 = 0; k0 < K; k0 += 32) {
    __syncthreads();
#pragma unroll
    for (int c = 0; c < 2; c++) {
      int s = c * 4 + w;             // 16-row segment (1024B of LDS)
      const __hip_bfloat16* gA = A + (size_t)(row0 + s * 16 + sr) * K + k0 + sk;
      __builtin_amdgcn_global_load_lds((gas1_t)gA, (las3_t)((char*)As + s * 1024), 16, 0, 0);
      const __hip_bfloat16* gB = Bt + (size_t)(col0 + s * 16 + sr) * K + k0 + sk;
      __builtin_amdgcn_global_load_lds((gas1_t)gB, (las3_t)((char*)Bs + s * 1024), 16, 0, 0);
    }
    __syncthreads();
    bf16x8 af[4], bfr[4];
#pragma unroll
    for (int i = 0; i < 4; i++)
      af[i] = *(const bf16x8*)((const char*)As + (((wm * 64 + i * 16 + l16) * 32 + quad * 8) << 1));
#pragma unroll
    for (int j = 0; j < 4; j++)
      bfr[j] = *(const bf16x8*)((const char*)Bs + (((wn * 64 + j * 16 + l16) * 32 + quad * 8) << 1));
#pragma unroll
    for (int i = 0; i < 4; i++)
#pragma unroll
      for (int j = 0; j < 4; j++)
        acc[i][j] = __builtin_amdgcn_mfma_f32_16x16x32_bf16(af[i], bfr[j], acc[i][j], 0, 0, 0);
  }
#pragma unroll
  for (int i = 0; i < 4; i++) {
    int rowb = row0 + wm * 64 + i * 16 + quad * 4;
#pragma unroll
    for (int j = 0; j < 4; j++) {
      int col = col0 + wn * 64 + j * 16 + l16;
#pragma unroll
      for (int r = 0; r < 4; r++)
        C[(size_t)(rowb + r) * N + col] = acc[i][j][r];
    }
  }
}

// ---------------- LayerNorm of k over DK (no affine) ----------------
__global__ __launch_bounds__(256) void ln_kernel(const float* __restrict__ qkv, float* __restrict__ kn) {
  int gid = blockIdx.x * 4 + (threadIdx.x >> 6);  // row in [0, B*L*H)
  int lane = threadIdx.x & 63;
  int bl = gid >> 4, h = gid & 15;
  float v = qkv[(size_t)(bl * 3 + 1) * DH + h * DKH + lane];
  float s = v;
#pragma unroll
  for (int off = 1; off < 64; off <<= 1) s += __shfl_xor(s, off);
  float mu = s * (1.f / 64.f);
  float d = v - mu;
  float s2 = d * d;
#pragma unroll
  for (int off = 1; off < 64; off <<= 1) s2 += __shfl_xor(s2, off);
  float var = s2 * (1.f / 64.f);
  kn[(size_t)gid * 64 + lane] = d * rsqrtf(var + 1e-5f);
}

// ---------------- causal flash attention (fp32), raw k ----------------
__global__ __launch_bounds__(256) void attn_kernel(const float* __restrict__ qkv, float* __restrict__ so) {
  const int it = blockIdx.x, h = blockIdx.y, bb = blockIdx.z;
  const int tid = threadIdx.x;
  const int r = tid >> 2, grp = tid & 3;
  __shared__ float Qs[64][68];
  __shared__ float Ks[32][68];
  __shared__ float Vs[32][68];
  __shared__ float Ps[64][36];
  const int i0 = it * 64;
#pragma unroll
  for (int i = 0; i < 16; i++) {
    int idx = tid + 256 * i;
    int rr = idx >> 6, e = idx & 63;
    Qs[rr][e] = qkv[((size_t)(bb * LQ + i0 + rr) * 3 + 0) * DH + h * DKH + e];
  }
  float m = -1e30f, l = 0.f;
  float o[16];
#pragma unroll
  for (int i = 0; i < 16; i++) o[i] = 0.f;
  __syncthreads();
  const int ntiles = (it + 1) * 2;
  for (int jt = 0; jt < ntiles; jt++) {
    const int j0 = jt * 32;
#pragma unroll
    for (int i = 0; i < 8; i++) {
      int idx = tid + 256 * i;
      int kk = idx >> 6, e = idx & 63;
      Ks[kk][e] = qkv[((size_t)(bb * LQ + j0 + kk) * 3 + 1) * DH + h * DKH + e];
      Vs[kk][e] = qkv[((size_t)(bb * LQ + j0 + kk) * 3 + 2) * DH + h * DKH + e];
    }
    __syncthreads();
    float acc[8];
#pragma unroll
    for (int mm = 0; mm < 8; mm++) acc[mm] = 0.f;
#pragma unroll
    for (int e4 = 0; e4 < 16; e4++) {
      float4 qv = *(const float4*)&Qs[r][e4 * 4];
#pragma unroll
      for (int mm = 0; mm < 8; mm++) {
        float4 kv = *(const float4*)&Ks[mm * 4 + grp][e4 * 4];
        acc[mm] = fmaf(qv.x, kv.x, acc[mm]);
        acc[mm] = fmaf(qv.y, kv.y, acc[mm]);
        acc[mm] = fmaf(qv.z, kv.z, acc[mm]);
        acc[mm] = fmaf(qv.w, kv.w, acc[mm]);
      }
    }
    float tmax = -1e30f;
#pragma unroll
    for (int mm = 0; mm < 8; mm++) {
      int k = mm * 4 + grp;
      acc[mm] *= 0.125f;
      if (j0 + k > i0 + r) acc[mm] = -1e30f;
      tmax = fmaxf(tmax, acc[mm]);
    }
    tmax = fmaxf(tmax, __shfl_xor(tmax, 1));
    tmax = fmaxf(tmax, __shfl_xor(tmax, 2));
    float mnew = fmaxf(m, tmax);
    float alpha = expf(m - mnew);
    float tsum = 0.f;
#pragma unroll
    for (int mm = 0; mm < 8; mm++) {
      float pv = expf(acc[mm] - mnew);
      Ps[r][mm * 4 + grp] = pv;
      tsum += pv;
    }
    tsum += __shfl_xor(tsum, 1);
    tsum += __shfl_xor(tsum, 2);
    l = l * alpha + tsum;
    m = mnew;
#pragma unroll
    for (int i = 0; i < 16; i++) o[i] *= alpha;
#pragma unroll
    for (int k = 0; k < 32; k++) {
      float pk = Ps[r][k];
#pragma unroll
      for (int i = 0; i < 16; i++) o[i] = fmaf(pk, Vs[k][grp * 16 + i], o[i]);
    }
    __syncthreads();
  }
  float inv = 1.f / l;
  float* op = &so[(size_t)(bb * LQ + i0 + r) * DH + h * DKH + grp * 16];
#pragma unroll
  for (int i4 = 0; i4 < 4; i4++) {
    float4 c = {o[i4 * 4] * inv, o[i4 * 4 + 1] * inv, o[i4 * 4 + 2] * inv, o[i4 * 4 + 3] * inv};
    *(float4*)(op + i4 * 4) = c;
  }
}

// ---------------- STP scan: 2048 independent row-sequences; 64 blocks x 32 rows ----------------
__global__ __launch_bounds__(256) void scan_kernel(
    const float* __restrict__ qkv, const float* __restrict__ kn, const float* __restrict__ W_LTM,
    const float* __restrict__ ret_g, const float* __restrict__ co_g, float* __restrict__ stp) {
  const int bh = blockIdx.x >> 1;
  const int half = blockIdx.x & 1;
  const int bb = bh >> 4, h = bh & 15;
  const int tid = threadIdx.x;
  const int dl = tid >> 3;   // 0..31 local row
  const int j = tid & 7;     // 8 col-groups of 8
  const int d = half * 32 + dl;
  float F[8], R[8], Cc[8], W[8];
  const int base = h * 4096 + d * 64 + j * 8;
#pragma unroll
  for (int i = 0; i < 8; i++) {
    F[i] = 0.f;
    R[i] = ret_g[base + i];
    Cc[i] = co_g[base + i];
    W[i] = W_LTM[base + i];
  }
  __shared__ float qb[2][8][64], kb[2][8][64], vb[2][8][64];

  float ld[6];
#pragma unroll
  for (int i = 0; i < 6; i++) {
    int idx = tid + 256 * i;
    int which = idx >> 9, rem = idx & 511, s = rem >> 6, e = rem & 63;
    int t = s;
    if (which == 0)      ld[i] = qkv[((size_t)(bb * LQ + t) * 3 + 0) * DH + h * DKH + e];
    else if (which == 1) ld[i] = kn[((size_t)(bb * LQ + t) * NH + h) * DKH + e];
    else                 ld[i] = qkv[((size_t)(bb * LQ + t) * 3 + 2) * DH + h * DKH + e];
  }
#pragma unroll
  for (int i = 0; i < 6; i++) {
    int idx = tid + 256 * i;
    int which = idx >> 9, rem = idx & 511, s = rem >> 6, e = rem & 63;
    if (which == 0) qb[0][s][e] = ld[i];
    else if (which == 1) kb[0][s][e] = ld[i];
    else vb[0][s][e] = ld[i];
  }
  __syncthreads();

  for (int c = 0; c < 128; c++) {
    const int p = c & 1;
    float l2[6];
    if (c < 127) {
      int t0 = (c + 1) * 8;
#pragma unroll
      for (int i = 0; i < 6; i++) {
        int idx = tid + 256 * i;
        int which = idx >> 9, rem = idx & 511, s = rem >> 6, e = rem & 63;
        int t = t0 + s;
        if (which == 0)      l2[i] = qkv[((size_t)(bb * LQ + t) * 3 + 0) * DH + h * DKH + e];
        else if (which == 1) l2[i] = kn[((size_t)(bb * LQ + t) * NH + h) * DKH + e];
        else                 l2[i] = qkv[((size_t)(bb * LQ + t) * 3 + 2) * DH + h * DKH + e];
      }
    }
#pragma unroll
    for (int s = 0; s < 8; s++) {
      float vd = vb[p][s][d];
      float yp = 0.f;
#pragma unroll
      for (int i = 0; i < 8; i++) {
        float ke = kb[p][s][j * 8 + i];
        F[i] = fmaf(Cc[i], vd * ke, R[i] * F[i]);
        yp = fmaf(W[i] + F[i], qb[p][s][j * 8 + i], yp);
      }
      yp += __shfl_xor(yp, 1);
      yp += __shfl_xor(yp, 2);
      yp += __shfl_xor(yp, 4);
      if (j == 0) stp[((size_t)(bb * LQ + c * 8 + s) * NH + h) * DKH + d] = yp;
    }
    if (c < 127) {
      const int pn = p ^ 1;
#pragma unroll
      for (int i = 0; i < 6; i++) {
        int idx = tid + 256 * i;
        int which = idx >> 9, rem = idx & 511, s = rem >> 6, e = rem & 63;
        if (which == 0) qb[pn][s][e] = l2[i];
        else if (which == 1) kb[pn][s][e] = l2[i];
        else vb[pn][s][e] = l2[i];
      }
    }
    __syncthreads();
  }
}

extern "C" void kernel_launch(void* const* d_in, const int* in_sizes, int n_in,
                              void* d_out, int out_size, void* d_ws, size_t ws_size,
                              hipStream_t stream) {
  (void)in_sizes; (void)n_in; (void)out_size; (void)ws_size;
  const float* x        = (const float*)d_in[0];
  const float* W_qkv    = (const float*)d_in[1];
  const float* W_o      = (const float*)d_in[2];
  const float* W_LTM    = (const float*)d_in[3];
  const float* V_gs     = (const float*)d_in[4];
  const float* V_T0     = (const float*)d_in[5];
  const float* beta_tau = (const float*)d_in[6];
  const float* beta_gm  = (const float*)d_in[7];
  const float* C_ch     = (const float*)d_in[8];
  const float* gamma_   = (const float*)d_in[9];
  const float* alpha_p  = (const float*)d_in[10];
  const float* IC_thr   = (const float*)d_in[11];
  const float* gate     = (const float*)d_in[12];

  float* ws  = (float*)d_ws;
  float* qkv = ws;                    // 6291456 f32
  float* kn  = qkv + 6291456;         // 2097152 f32
  float* so  = kn + 2097152;          // 2097152 f32
  float* stp = so + 2097152;          // 2097152 f32 (8 MB)
  float* ret = stp + 2097152;         // 65536 f32
  float* co  = ret + 65536;           // 65536 f32
  float* g   = co + 65536;            // 64 f32
  __hip_bfloat16* xb   = (__hip_bfloat16*)(g + 64);   // 2097152 bf16 (4 MB)
  __hip_bfloat16* wot  = xb + 2097152;                // 1048576 bf16 (2 MB)
  __hip_bfloat16* mixb = xb;                          // alias: xb dead after qkv GEMM
  __hip_bfloat16* wqt  = (__hip_bfloat16*)stp;        // alias: 6 MB <= stp's 8 MB; stp written after qkv GEMM
  float* out = (float*)d_out;

  physics_kernel<<<256, 256, 0, stream>>>(W_LTM, V_gs, V_T0, beta_tau, beta_gm, C_ch,
                                          gamma_, alpha_p, IC_thr, gate, ret, co, g);
  cvt_kernel<<<2048, 256, 0, stream>>>(x, xb);                       // 2048x1024
  tcvt_kernel<<<dim3(96, 32), 256, 0, stream>>>(W_qkv, wqt, 1024, 3072);
  tcvt_kernel<<<dim3(32, 32), 256, 0, stream>>>(W_o, wot, 1024, 1024);
  gemm_bt_kernel<<<dim3(24, 16), 256, 0, stream>>>(xb, wqt, qkv, 2048, 3072, 1024);
  ln_kernel<<<8192, 256, 0, stream>>>(qkv, kn);
  attn_kernel<<<dim3(16, 16, 2), 256, 0, stream>>>(qkv, so);
  scan_kernel<<<64, 256, 0, stream>>>(qkv, kn, W_LTM, ret, co, stp);
  mix_kernel<<<2048, 256, 0, stream>>>(so, stp, g, mixb);
  gemm_bt_kernel<<<dim3(8, 16), 256, 0, stream>>>(mixb, wot, out, 2048, 1024, 1024);
}

// Round 3
// 394.309 us; speedup vs baseline: 2.1914x; 1.4927x over previous
//
#include <hip/hip_runtime.h>
#include <hip/hip_bf16.h>
#include <math.h>

#define LQ 1024
#define DH 1024
#define NH 16
#define DKH 64

typedef __bf16 bf16x8 __attribute__((ext_vector_type(8)));
typedef float f32x4 __attribute__((ext_vector_type(4)));
typedef const unsigned int __attribute__((address_space(1)))* gas1_t;
typedef unsigned int __attribute__((address_space(3)))* las3_t;

// ---------------- physics precompute: retention, retention^64, coeff, gate sigmoid ----------------
__global__ __launch_bounds__(256) void physics_kernel(
    const float* __restrict__ W_LTM, const float* __restrict__ V_gs, const float* __restrict__ V_T0,
    const float* __restrict__ beta_tau, const float* __restrict__ beta_gm, const float* __restrict__ C_ch,
    const float* __restrict__ gamma_, const float* __restrict__ alpha_ppd, const float* __restrict__ IC_thr,
    const float* __restrict__ gate, float* __restrict__ ret, float* __restrict__ ret64,
    float* __restrict__ co, float* __restrict__ g_out) {
  int idx = blockIdx.x * 256 + threadIdx.x;      // 65536 = H*DK*DK
  int h = idx >> 12;
  float w = W_LTM[idx];
  float veff = V_gs[h] - V_T0[h] + w;
  float sp = fmaxf(veff, 0.f) + log1pf(expf(-fabsf(veff)));   // stable softplus
  float gch = beta_tau[h] * sp;
  float e1 = gch / C_ch[h];
  float retv = expf(-e1);
  float sig = 1.f / (1.f + expf(-veff));
  float G = beta_gm[h] * sp * sig;
  float sm = tanhf(alpha_ppd[0] * (gch - IC_thr[0]));
  ret[idx] = retv;
  ret64[idx] = expf(-64.f * e1);
  co[idx] = gamma_[h] * sm * G;
  if (idx < NH) g_out[idx] = 1.f / (1.f + expf(-gate[idx]));
}

// ---------------- fp32 -> bf16 elementwise (x) ----------------
__global__ __launch_bounds__(256) void cvt_kernel(const float* __restrict__ in, __hip_bfloat16* __restrict__ out) {
  size_t i = (size_t)(blockIdx.x * 256 + threadIdx.x) * 4;
  float4 v = *(const float4*)(in + i);
  __hip_bfloat16 t[4] = {__float2bfloat16(v.x), __float2bfloat16(v.y),
                         __float2bfloat16(v.z), __float2bfloat16(v.w)};
  *(uint2*)(out + i) = *(uint2*)t;
}

// ---------------- fp32 [K][N] -> bf16 [N][K] transpose-convert ----------------
__global__ __launch_bounds__(256) void tcvt_kernel(const float* __restrict__ W, __hip_bfloat16* __restrict__ Wt,
                                                   int K, int N) {
  __shared__ float t[32][33];
  int n0 = blockIdx.x * 32, k0 = blockIdx.y * 32;
  int r = threadIdx.x >> 5, c = threadIdx.x & 31;
#pragma unroll
  for (int i = 0; i < 4; i++) t[r + 8 * i][c] = W[(size_t)(k0 + r + 8 * i) * N + n0 + c];
  __syncthreads();
#pragma unroll
  for (int i = 0; i < 4; i++)
    Wt[(size_t)(n0 + r + 8 * i) * K + k0 + c] = __float2bfloat16(t[c][r + 8 * i]);
}

// ---------------- gate mix -> bf16 ----------------
__global__ __launch_bounds__(256) void mix_kernel(const float* __restrict__ so, const float* __restrict__ stp,
                                                  const float* __restrict__ g, __hip_bfloat16* __restrict__ out) {
  size_t base = (size_t)(blockIdx.x * 256 + threadIdx.x) * 4;
  float gv = g[(base >> 6) & 15];
  float4 a = *(const float4*)(so + base);
  float4 b = *(const float4*)(stp + base);
  __hip_bfloat16 t[4] = {__float2bfloat16(gv * a.x + (1.f - gv) * b.x),
                         __float2bfloat16(gv * a.y + (1.f - gv) * b.y),
                         __float2bfloat16(gv * a.z + (1.f - gv) * b.z),
                         __float2bfloat16(gv * a.w + (1.f - gv) * b.w)};
  *(uint2*)(out + base) = *(uint2*)t;
}

// ---------------- bf16 MFMA GEMM (m97 structure): C[M,N] = A[M,K] * Bt[N,K]^T ----------------
__global__ __launch_bounds__(256) void gemm_bt_kernel(
    const __hip_bfloat16* __restrict__ A, const __hip_bfloat16* __restrict__ Bt,
    float* __restrict__ C, int M, int N, int K) {
  __shared__ unsigned short As[128 * 32];
  __shared__ unsigned short Bs[128 * 32];
  const int tid = threadIdx.x;
  const int w = tid >> 6, lane = tid & 63;
  const int quad = lane >> 4, l16 = lane & 15;
  const int wm = w & 1, wn = w >> 1;
  const int row0 = blockIdx.y * 128, col0 = blockIdx.x * 128;
  const int sr = lane >> 2;
  const int sk = (lane & 3) * 8;
  f32x4 acc[4][4];
#pragma unroll
  for (int i = 0; i < 4; i++)
#pragma unroll
    for (int j = 0; j < 4; j++) acc[i][j] = (f32x4){0.f, 0.f, 0.f, 0.f};

  for (int k0 = 0; k0 < K; k0 += 32) {
    __syncthreads();
#pragma unroll
    for (int c = 0; c < 2; c++) {
      int s = c * 4 + w;
      const __hip_bfloat16* gA = A + (size_t)(row0 + s * 16 + sr) * K + k0 + sk;
      __builtin_amdgcn_global_load_lds((gas1_t)gA, (las3_t)((char*)As + s * 1024), 16, 0, 0);
      const __hip_bfloat16* gB = Bt + (size_t)(col0 + s * 16 + sr) * K + k0 + sk;
      __builtin_amdgcn_global_load_lds((gas1_t)gB, (las3_t)((char*)Bs + s * 1024), 16, 0, 0);
    }
    __syncthreads();
    bf16x8 af[4], bfr[4];
#pragma unroll
    for (int i = 0; i < 4; i++)
      af[i] = *(const bf16x8*)((const char*)As + (((wm * 64 + i * 16 + l16) * 32 + quad * 8) << 1));
#pragma unroll
    for (int j = 0; j < 4; j++)
      bfr[j] = *(const bf16x8*)((const char*)Bs + (((wn * 64 + j * 16 + l16) * 32 + quad * 8) << 1));
#pragma unroll
    for (int i = 0; i < 4; i++)
#pragma unroll
      for (int j = 0; j < 4; j++)
        acc[i][j] = __builtin_amdgcn_mfma_f32_16x16x32_bf16(af[i], bfr[j], acc[i][j], 0, 0, 0);
  }
#pragma unroll
  for (int i = 0; i < 4; i++) {
    int rowb = row0 + wm * 64 + i * 16 + quad * 4;
#pragma unroll
    for (int j = 0; j < 4; j++) {
      int col = col0 + wn * 64 + j * 16 + l16;
#pragma unroll
      for (int r = 0; r < 4; r++)
        C[(size_t)(rowb + r) * N + col] = acc[i][j][r];
    }
  }
}

// ---------------- LayerNorm of k over DK (no affine) ----------------
__global__ __launch_bounds__(256) void ln_kernel(const float* __restrict__ qkv, float* __restrict__ kn) {
  int gid = blockIdx.x * 4 + (threadIdx.x >> 6);
  int lane = threadIdx.x & 63;
  int bl = gid >> 4, h = gid & 15;
  float v = qkv[(size_t)(bl * 3 + 1) * DH + h * DKH + lane];
  float s = v;
#pragma unroll
  for (int off = 1; off < 64; off <<= 1) s += __shfl_xor(s, off);
  float mu = s * (1.f / 64.f);
  float d = v - mu;
  float s2 = d * d;
#pragma unroll
  for (int off = 1; off < 64; off <<= 1) s2 += __shfl_xor(s2, off);
  float var = s2 * (1.f / 64.f);
  kn[(size_t)gid * 64 + lane] = d * rsqrtf(var + 1e-5f);
}

// ---------------- causal flash attention (fp32), raw k ----------------
__global__ __launch_bounds__(256) void attn_kernel(const float* __restrict__ qkv, float* __restrict__ so) {
  const int it = blockIdx.x, h = blockIdx.y, bb = blockIdx.z;
  const int tid = threadIdx.x;
  const int r = tid >> 2, grp = tid & 3;
  __shared__ float Qs[64][68];
  __shared__ float Ks[32][68];
  __shared__ float Vs[32][68];
  __shared__ float Ps[64][36];
  const int i0 = it * 64;
#pragma unroll
  for (int i = 0; i < 16; i++) {
    int idx = tid + 256 * i;
    int rr = idx >> 6, e = idx & 63;
    Qs[rr][e] = qkv[((size_t)(bb * LQ + i0 + rr) * 3 + 0) * DH + h * DKH + e];
  }
  float m = -1e30f, l = 0.f;
  float o[16];
#pragma unroll
  for (int i = 0; i < 16; i++) o[i] = 0.f;
  __syncthreads();
  const int ntiles = (it + 1) * 2;
  for (int jt = 0; jt < ntiles; jt++) {
    const int j0 = jt * 32;
#pragma unroll
    for (int i = 0; i < 8; i++) {
      int idx = tid + 256 * i;
      int kk = idx >> 6, e = idx & 63;
      Ks[kk][e] = qkv[((size_t)(bb * LQ + j0 + kk) * 3 + 1) * DH + h * DKH + e];
      Vs[kk][e] = qkv[((size_t)(bb * LQ + j0 + kk) * 3 + 2) * DH + h * DKH + e];
    }
    __syncthreads();
    float acc[8];
#pragma unroll
    for (int mm = 0; mm < 8; mm++) acc[mm] = 0.f;
#pragma unroll
    for (int e4 = 0; e4 < 16; e4++) {
      float4 qv = *(const float4*)&Qs[r][e4 * 4];
#pragma unroll
      for (int mm = 0; mm < 8; mm++) {
        float4 kv = *(const float4*)&Ks[mm * 4 + grp][e4 * 4];
        acc[mm] = fmaf(qv.x, kv.x, acc[mm]);
        acc[mm] = fmaf(qv.y, kv.y, acc[mm]);
        acc[mm] = fmaf(qv.z, kv.z, acc[mm]);
        acc[mm] = fmaf(qv.w, kv.w, acc[mm]);
      }
    }
    float tmax = -1e30f;
#pragma unroll
    for (int mm = 0; mm < 8; mm++) {
      int k = mm * 4 + grp;
      acc[mm] *= 0.125f;
      if (j0 + k > i0 + r) acc[mm] = -1e30f;
      tmax = fmaxf(tmax, acc[mm]);
    }
    tmax = fmaxf(tmax, __shfl_xor(tmax, 1));
    tmax = fmaxf(tmax, __shfl_xor(tmax, 2));
    float mnew = fmaxf(m, tmax);
    float alpha = expf(m - mnew);
    float tsum = 0.f;
#pragma unroll
    for (int mm = 0; mm < 8; mm++) {
      float pv = expf(acc[mm] - mnew);
      Ps[r][mm * 4 + grp] = pv;
      tsum += pv;
    }
    tsum += __shfl_xor(tsum, 1);
    tsum += __shfl_xor(tsum, 2);
    l = l * alpha + tsum;
    m = mnew;
#pragma unroll
    for (int i = 0; i < 16; i++) o[i] *= alpha;
#pragma unroll
    for (int k = 0; k < 32; k++) {
      float pk = Ps[r][k];
#pragma unroll
      for (int i = 0; i < 16; i++) o[i] = fmaf(pk, Vs[k][grp * 16 + i], o[i]);
    }
    __syncthreads();
  }
  float inv = 1.f / l;
  float* op = &so[(size_t)(bb * LQ + i0 + r) * DH + h * DKH + grp * 16];
#pragma unroll
  for (int i4 = 0; i4 < 4; i4++) {
    float4 c = {o[i4 * 4] * inv, o[i4 * 4 + 1] * inv, o[i4 * 4 + 2] * inv, o[i4 * 4 + 3] * inv};
    *(float4*)(op + i4 * 4) = c;
  }
}

// ============ chunked STP scan: T=64, 16 chunks ============
// Pass 1: per-chunk local decayed sum S_c (chunks 0..14), recurrence from zero.
__global__ __launch_bounds__(256) void state_kernel(
    const float* __restrict__ qkv, const float* __restrict__ kn,
    const float* __restrict__ ret_g, const float* __restrict__ co_g, float* __restrict__ S) {
  const int bh = blockIdx.x >> 1;
  const int half = blockIdx.x & 1;
  const int c = blockIdx.y;                 // 0..14
  const int bb = bh >> 4, h = bh & 15;
  const int tid = threadIdx.x;
  const int dl = tid >> 3, j = tid & 7;
  const int d = half * 32 + dl;
  float F[8], R[8], Cc[8];
  const int base = h * 4096 + d * 64 + j * 8;
#pragma unroll
  for (int i = 0; i < 8; i++) {
    F[i] = 0.f;
    R[i] = ret_g[base + i];
    Cc[i] = co_g[base + i];
  }
  __shared__ float kb[2][8][64], vb[2][8][64];
  const int t00 = c * 64;
  // preload sub-chunk 0 (4 elems/thread: 2 tensors x 8 steps x 64)
  {
    float ld[4];
#pragma unroll
    for (int i = 0; i < 4; i++) {
      int idx = tid + 256 * i;
      int which = idx >> 9, rem = idx & 511, s = rem >> 6, e = rem & 63;
      int t = t00 + s;
      if (which == 0) ld[i] = kn[((size_t)(bb * LQ + t) * NH + h) * DKH + e];
      else            ld[i] = qkv[((size_t)(bb * LQ + t) * 3 + 2) * DH + h * DKH + e];
    }
#pragma unroll
    for (int i = 0; i < 4; i++) {
      int idx = tid + 256 * i;
      int which = idx >> 9, rem = idx & 511, s = rem >> 6, e = rem & 63;
      if (which == 0) kb[0][s][e] = ld[i];
      else            vb[0][s][e] = ld[i];
    }
  }
  __syncthreads();
  for (int sc = 0; sc < 8; sc++) {
    const int p = sc & 1;
    float l2[4];
    if (sc < 7) {
      int t0 = t00 + (sc + 1) * 8;
#pragma unroll
      for (int i = 0; i < 4; i++) {
        int idx = tid + 256 * i;
        int which = idx >> 9, rem = idx & 511, s = rem >> 6, e = rem & 63;
        int t = t0 + s;
        if (which == 0) l2[i] = kn[((size_t)(bb * LQ + t) * NH + h) * DKH + e];
        else            l2[i] = qkv[((size_t)(bb * LQ + t) * 3 + 2) * DH + h * DKH + e];
      }
    }
#pragma unroll
    for (int s = 0; s < 8; s++) {
      float vd = vb[p][s][d];
#pragma unroll
      for (int i = 0; i < 8; i++) {
        float ke = kb[p][s][j * 8 + i];
        F[i] = fmaf(Cc[i] * vd, ke, R[i] * F[i]);
      }
    }
    if (sc < 7) {
      const int pn = p ^ 1;
#pragma unroll
      for (int i = 0; i < 4; i++) {
        int idx = tid + 256 * i;
        int which = idx >> 9, rem = idx & 511, s = rem >> 6, e = rem & 63;
        if (which == 0) kb[pn][s][e] = l2[i];
        else            vb[pn][s][e] = l2[i];
      }
    }
    __syncthreads();
  }
  const size_t sb = ((size_t)c * 2048 + ((size_t)bb * 16 + h) * 64 + d) * 64 + j * 8;
#pragma unroll
  for (int i = 0; i < 8; i++) S[sb + i] = F[i];
}

// Pass 2: serial combine over 16 chunks; 131072 independent scalar scans.
__global__ __launch_bounds__(256) void combine_kernel(
    const float* __restrict__ S, const float* __restrict__ ret64, float* __restrict__ Fs) {
  int n = blockIdx.x * 256 + threadIdx.x;   // 0..131071 = ((bb*16+h)*64+d)*64+e
  float r64 = ret64[n & 65535];
  float F = 0.f;
  Fs[n] = 0.f;
#pragma unroll
  for (int c = 1; c < 16; c++) {
    F = fmaf(r64, F, S[(size_t)(c - 1) * 131072 + n]);
    Fs[(size_t)c * 131072 + n] = F;
  }
}

// Pass 3: outputs, seeded from Fs[c]; 16 chunks x 64 row-blocks = 1024 blocks.
__global__ __launch_bounds__(256) void scan_out_kernel(
    const float* __restrict__ qkv, const float* __restrict__ kn, const float* __restrict__ W_LTM,
    const float* __restrict__ ret_g, const float* __restrict__ co_g, const float* __restrict__ Fs,
    float* __restrict__ stp) {
  const int bh = blockIdx.x >> 1;
  const int half = blockIdx.x & 1;
  const int c = blockIdx.y;                 // 0..15
  const int bb = bh >> 4, h = bh & 15;
  const int tid = threadIdx.x;
  const int dl = tid >> 3, j = tid & 7;
  const int d = half * 32 + dl;
  float F[8], R[8], Cc[8], W[8];
  const int base = h * 4096 + d * 64 + j * 8;
  const size_t nbase = (size_t)c * 131072 + (((size_t)bb * 16 + h) * 64 + d) * 64 + j * 8;
#pragma unroll
  for (int i = 0; i < 8; i++) {
    F[i] = Fs[nbase + i];
    R[i] = ret_g[base + i];
    Cc[i] = co_g[base + i];
    W[i] = W_LTM[base + i];
  }
  __shared__ float qb[2][8][64], kb[2][8][64], vb[2][8][64];
  const int t00 = c * 64;
  {
    float ld[6];
#pragma unroll
    for (int i = 0; i < 6; i++) {
      int idx = tid + 256 * i;
      int which = idx >> 9, rem = idx & 511, s = rem >> 6, e = rem & 63;
      int t = t00 + s;
      if (which == 0)      ld[i] = qkv[((size_t)(bb * LQ + t) * 3 + 0) * DH + h * DKH + e];
      else if (which == 1) ld[i] = kn[((size_t)(bb * LQ + t) * NH + h) * DKH + e];
      else                 ld[i] = qkv[((size_t)(bb * LQ + t) * 3 + 2) * DH + h * DKH + e];
    }
#pragma unroll
    for (int i = 0; i < 6; i++) {
      int idx = tid + 256 * i;
      int which = idx >> 9, rem = idx & 511, s = rem >> 6, e = rem & 63;
      if (which == 0) qb[0][s][e] = ld[i];
      else if (which == 1) kb[0][s][e] = ld[i];
      else vb[0][s][e] = ld[i];
    }
  }
  __syncthreads();
  for (int sc = 0; sc < 8; sc++) {
    const int p = sc & 1;
    float l2[6];
    if (sc < 7) {
      int t0 = t00 + (sc + 1) * 8;
#pragma unroll
      for (int i = 0; i < 6; i++) {
        int idx = tid + 256 * i;
        int which = idx >> 9, rem = idx & 511, s = rem >> 6, e = rem & 63;
        int t = t0 + s;
        if (which == 0)      l2[i] = qkv[((size_t)(bb * LQ + t) * 3 + 0) * DH + h * DKH + e];
        else if (which == 1) l2[i] = kn[((size_t)(bb * LQ + t) * NH + h) * DKH + e];
        else                 l2[i] = qkv[((size_t)(bb * LQ + t) * 3 + 2) * DH + h * DKH + e];
      }
    }
#pragma unroll
    for (int s = 0; s < 8; s++) {
      float vd = vb[p][s][d];
      float yp = 0.f;
#pragma unroll
      for (int i = 0; i < 8; i++) {
        float ke = kb[p][s][j * 8 + i];
        F[i] = fmaf(Cc[i] * vd, ke, R[i] * F[i]);
        yp = fmaf(W[i] + F[i], qb[p][s][j * 8 + i], yp);
      }
      yp += __shfl_xor(yp, 1);
      yp += __shfl_xor(yp, 2);
      yp += __shfl_xor(yp, 4);
      if (j == 0) stp[((size_t)(bb * LQ + t00 + sc * 8 + s) * NH + h) * DKH + d] = yp;
    }
    if (sc < 7) {
      const int pn = p ^ 1;
#pragma unroll
      for (int i = 0; i < 6; i++) {
        int idx = tid + 256 * i;
        int which = idx >> 9, rem = idx & 511, s = rem >> 6, e = rem & 63;
        if (which == 0) qb[pn][s][e] = l2[i];
        else if (which == 1) kb[pn][s][e] = l2[i];
        else vb[pn][s][e] = l2[i];
      }
    }
    __syncthreads();
  }
}

extern "C" void kernel_launch(void* const* d_in, const int* in_sizes, int n_in,
                              void* d_out, int out_size, void* d_ws, size_t ws_size,
                              hipStream_t stream) {
  (void)in_sizes; (void)n_in; (void)out_size; (void)ws_size;
  const float* x        = (const float*)d_in[0];
  const float* W_qkv    = (const float*)d_in[1];
  const float* W_o      = (const float*)d_in[2];
  const float* W_LTM    = (const float*)d_in[3];
  const float* V_gs     = (const float*)d_in[4];
  const float* V_T0     = (const float*)d_in[5];
  const float* beta_tau = (const float*)d_in[6];
  const float* beta_gm  = (const float*)d_in[7];
  const float* C_ch     = (const float*)d_in[8];
  const float* gamma_   = (const float*)d_in[9];
  const float* alpha_p  = (const float*)d_in[10];
  const float* IC_thr   = (const float*)d_in[11];
  const float* gate     = (const float*)d_in[12];

  float* ws  = (float*)d_ws;
  float* qkv   = ws;                    // 6291456 f32
  float* kn    = qkv + 6291456;         // 2097152 f32
  float* so    = kn + 2097152;          // 2097152 f32
  float* stp   = so + 2097152;          // 2097152 f32 (8 MB)
  float* ret   = stp + 2097152;         // 65536
  float* ret64 = ret + 65536;           // 65536
  float* co    = ret64 + 65536;         // 65536
  float* g     = co + 65536;            // 64
  __hip_bfloat16* xb  = (__hip_bfloat16*)(g + 64);   // 2097152 bf16
  __hip_bfloat16* wot = xb + 2097152;                // 1048576 bf16
  float* Sbuf = (float*)(wot + 1048576);             // 15*131072 = 1966080 f32
  float* Fs   = Sbuf + 1966080;                      // 16*131072 = 2097152 f32
  __hip_bfloat16* mixb = xb;                          // alias: xb dead after qkv GEMM
  __hip_bfloat16* wqt  = (__hip_bfloat16*)stp;        // alias: stp written only in pass 3
  float* out = (float*)d_out;

  physics_kernel<<<256, 256, 0, stream>>>(W_LTM, V_gs, V_T0, beta_tau, beta_gm, C_ch,
                                          gamma_, alpha_p, IC_thr, gate, ret, ret64, co, g);
  cvt_kernel<<<2048, 256, 0, stream>>>(x, xb);
  tcvt_kernel<<<dim3(96, 32), 256, 0, stream>>>(W_qkv, wqt, 1024, 3072);
  tcvt_kernel<<<dim3(32, 32), 256, 0, stream>>>(W_o, wot, 1024, 1024);
  gemm_bt_kernel<<<dim3(24, 16), 256, 0, stream>>>(xb, wqt, qkv, 2048, 3072, 1024);
  ln_kernel<<<8192, 256, 0, stream>>>(qkv, kn);
  attn_kernel<<<dim3(16, 16, 2), 256, 0, stream>>>(qkv, so);
  state_kernel<<<dim3(64, 15), 256, 0, stream>>>(qkv, kn, ret, co, Sbuf);
  combine_kernel<<<512, 256, 0, stream>>>(Sbuf, ret64, Fs);
  scan_out_kernel<<<dim3(64, 16), 256, 0, stream>>>(qkv, kn, W_LTM, ret, co, Fs, stp);
  mix_kernel<<<2048, 256, 0, stream>>>(so, stp, g, mixb);
  gemm_bt_kernel<<<dim3(8, 16), 256, 0, stream>>>(mixb, wot, out, 2048, 1024, 1024);
}

// Round 4
// 253.481 us; speedup vs baseline: 3.4089x; 1.5556x over previous
//
#include <hip/hip_runtime.h>
#include <hip/hip_bf16.h>
#include <math.h>

#define LQ 1024
#define DH 1024
#define NH 16
#define DKH 64

typedef __bf16 bf16x8 __attribute__((ext_vector_type(8)));
typedef float f32x4 __attribute__((ext_vector_type(4)));
typedef const unsigned int __attribute__((address_space(1)))* gas1_t;
typedef unsigned int __attribute__((address_space(3)))* las3_t;

// ---------------- physics precompute ----------------
__global__ __launch_bounds__(256) void physics_kernel(
    const float* __restrict__ W_LTM, const float* __restrict__ V_gs, const float* __restrict__ V_T0,
    const float* __restrict__ beta_tau, const float* __restrict__ beta_gm, const float* __restrict__ C_ch,
    const float* __restrict__ gamma_, const float* __restrict__ alpha_ppd, const float* __restrict__ IC_thr,
    const float* __restrict__ gate, float* __restrict__ ret, float* __restrict__ ret64,
    float* __restrict__ co, float* __restrict__ g_out) {
  int idx = blockIdx.x * 256 + threadIdx.x;
  int h = idx >> 12;
  float w = W_LTM[idx];
  float veff = V_gs[h] - V_T0[h] + w;
  float sp = fmaxf(veff, 0.f) + log1pf(expf(-fabsf(veff)));
  float gch = beta_tau[h] * sp;
  float e1 = gch / C_ch[h];
  float retv = expf(-e1);
  float sig = 1.f / (1.f + expf(-veff));
  float G = beta_gm[h] * sp * sig;
  float sm = tanhf(alpha_ppd[0] * (gch - IC_thr[0]));
  ret[idx] = retv;
  ret64[idx] = expf(-64.f * e1);
  co[idx] = gamma_[h] * sm * G;
  if (idx < NH) g_out[idx] = 1.f / (1.f + expf(-gate[idx]));
}

// ---------------- fp32 -> bf16 elementwise (x) ----------------
__global__ __launch_bounds__(256) void cvt_kernel(const float* __restrict__ in, __hip_bfloat16* __restrict__ out) {
  size_t i = (size_t)(blockIdx.x * 256 + threadIdx.x) * 4;
  float4 v = *(const float4*)(in + i);
  __hip_bfloat16 t[4] = {__float2bfloat16(v.x), __float2bfloat16(v.y),
                         __float2bfloat16(v.z), __float2bfloat16(v.w)};
  *(uint2*)(out + i) = *(uint2*)t;
}

// ---------------- fp32 [K][N] -> bf16 [N][K] transpose-convert ----------------
__global__ __launch_bounds__(256) void tcvt_kernel(const float* __restrict__ W, __hip_bfloat16* __restrict__ Wt,
                                                   int K, int N) {
  __shared__ float t[32][33];
  int n0 = blockIdx.x * 32, k0 = blockIdx.y * 32;
  int r = threadIdx.x >> 5, c = threadIdx.x & 31;
#pragma unroll
  for (int i = 0; i < 4; i++) t[r + 8 * i][c] = W[(size_t)(k0 + r + 8 * i) * N + n0 + c];
  __syncthreads();
#pragma unroll
  for (int i = 0; i < 4; i++)
    Wt[(size_t)(n0 + r + 8 * i) * K + k0 + c] = __float2bfloat16(t[c][r + 8 * i]);
}

// ---------------- gate mix -> bf16 ----------------
__global__ __launch_bounds__(256) void mix_kernel(const float* __restrict__ so, const float* __restrict__ stp,
                                                  const float* __restrict__ g, __hip_bfloat16* __restrict__ out) {
  size_t base = (size_t)(blockIdx.x * 256 + threadIdx.x) * 4;
  float gv = g[(base >> 6) & 15];
  float4 a = *(const float4*)(so + base);
  float4 b = *(const float4*)(stp + base);
  __hip_bfloat16 t[4] = {__float2bfloat16(gv * a.x + (1.f - gv) * b.x),
                         __float2bfloat16(gv * a.y + (1.f - gv) * b.y),
                         __float2bfloat16(gv * a.z + (1.f - gv) * b.z),
                         __float2bfloat16(gv * a.w + (1.f - gv) * b.w)};
  *(uint2*)(out + base) = *(uint2*)t;
}

// ---------------- bf16 MFMA GEMM (m97 structure): C[M,N] = A[M,K] * Bt[N,K]^T ----------------
__global__ __launch_bounds__(256) void gemm_bt_kernel(
    const __hip_bfloat16* __restrict__ A, const __hip_bfloat16* __restrict__ Bt,
    float* __restrict__ C, int M, int N, int K) {
  __shared__ unsigned short As[128 * 32];
  __shared__ unsigned short Bs[128 * 32];
  const int tid = threadIdx.x;
  const int w = tid >> 6, lane = tid & 63;
  const int quad = lane >> 4, l16 = lane & 15;
  const int wm = w & 1, wn = w >> 1;
  const int row0 = blockIdx.y * 128, col0 = blockIdx.x * 128;
  const int sr = lane >> 2;
  const int sk = (lane & 3) * 8;
  f32x4 acc[4][4];
#pragma unroll
  for (int i = 0; i < 4; i++)
#pragma unroll
    for (int j = 0; j < 4; j++) acc[i][j] = (f32x4){0.f, 0.f, 0.f, 0.f};

  for (int k0 = 0; k0 < K; k0 += 32) {
    __syncthreads();
#pragma unroll
    for (int c = 0; c < 2; c++) {
      int s = c * 4 + w;
      const __hip_bfloat16* gA = A + (size_t)(row0 + s * 16 + sr) * K + k0 + sk;
      __builtin_amdgcn_global_load_lds((gas1_t)gA, (las3_t)((char*)As + s * 1024), 16, 0, 0);
      const __hip_bfloat16* gB = Bt + (size_t)(col0 + s * 16 + sr) * K + k0 + sk;
      __builtin_amdgcn_global_load_lds((gas1_t)gB, (las3_t)((char*)Bs + s * 1024), 16, 0, 0);
    }
    __syncthreads();
    bf16x8 af[4], bfr[4];
#pragma unroll
    for (int i = 0; i < 4; i++)
      af[i] = *(const bf16x8*)((const char*)As + (((wm * 64 + i * 16 + l16) * 32 + quad * 8) << 1));
#pragma unroll
    for (int j = 0; j < 4; j++)
      bfr[j] = *(const bf16x8*)((const char*)Bs + (((wn * 64 + j * 16 + l16) * 32 + quad * 8) << 1));
#pragma unroll
    for (int i = 0; i < 4; i++)
#pragma unroll
      for (int j = 0; j < 4; j++)
        acc[i][j] = __builtin_amdgcn_mfma_f32_16x16x32_bf16(af[i], bfr[j], acc[i][j], 0, 0, 0);
  }
#pragma unroll
  for (int i = 0; i < 4; i++) {
    int rowb = row0 + wm * 64 + i * 16 + quad * 4;
#pragma unroll
    for (int j = 0; j < 4; j++) {
      int col = col0 + wn * 64 + j * 16 + l16;
#pragma unroll
      for (int r = 0; r < 4; r++)
        C[(size_t)(rowb + r) * N + col] = acc[i][j][r];
    }
  }
}

// ---------------- qkv fp32 -> qb(bf16,*0.125), kb(bf16), vt(bf16 transposed), kn(fp32 LN) ----------------
__global__ __launch_bounds__(256) void cvt_qkv_kernel(
    const float* __restrict__ qkv, __hip_bfloat16* __restrict__ qb, __hip_bfloat16* __restrict__ kb,
    __hip_bfloat16* __restrict__ vt, float* __restrict__ kn) {
  const int tc = blockIdx.x, h = blockIdx.y, b = blockIdx.z;
  const int bh = b * NH + h;
  const int tid = threadIdx.x;
  const int r = tid >> 2;        // local t 0..63
  const int q4 = tid & 3;        // d quarter
  const int t = tc * 64 + r;
  __shared__ float Ls[64][65];
  const size_t qrow = ((size_t)(b * LQ + t) * 3) * DH + h * DKH + q4 * 16;

  // ---- q: scale 0.125, bf16 ----
  {
    float4 v0 = *(const float4*)(qkv + qrow);
    float4 v1 = *(const float4*)(qkv + qrow + 4);
    float4 v2 = *(const float4*)(qkv + qrow + 8);
    float4 v3 = *(const float4*)(qkv + qrow + 12);
    float vv[16] = {v0.x, v0.y, v0.z, v0.w, v1.x, v1.y, v1.z, v1.w,
                    v2.x, v2.y, v2.z, v2.w, v3.x, v3.y, v3.z, v3.w};
    __hip_bfloat16 o[16];
#pragma unroll
    for (int i = 0; i < 16; i++) o[i] = __float2bfloat16(vv[i] * 0.125f);
    __hip_bfloat16* dst = qb + ((size_t)bh * LQ + t) * DKH + q4 * 16;
    *(uint4*)dst = *(uint4*)o;
    *(uint4*)(dst + 8) = *(uint4*)(o + 8);
  }
  // ---- k: raw bf16 + LayerNorm fp32 ----
  {
    const size_t krow = qrow + DH;
    float4 v0 = *(const float4*)(qkv + krow);
    float4 v1 = *(const float4*)(qkv + krow + 4);
    float4 v2 = *(const float4*)(qkv + krow + 8);
    float4 v3 = *(const float4*)(qkv + krow + 12);
    float vv[16] = {v0.x, v0.y, v0.z, v0.w, v1.x, v1.y, v1.z, v1.w,
                    v2.x, v2.y, v2.z, v2.w, v3.x, v3.y, v3.z, v3.w};
    __hip_bfloat16 o[16];
#pragma unroll
    for (int i = 0; i < 16; i++) o[i] = __float2bfloat16(vv[i]);
    __hip_bfloat16* dst = kb + ((size_t)bh * LQ + t) * DKH + q4 * 16;
    *(uint4*)dst = *(uint4*)o;
    *(uint4*)(dst + 8) = *(uint4*)(o + 8);
    float s1 = 0.f, s2 = 0.f;
#pragma unroll
    for (int i = 0; i < 16; i++) { s1 += vv[i]; s2 += vv[i] * vv[i]; }
    s1 += __shfl_xor(s1, 1); s2 += __shfl_xor(s2, 1);
    s1 += __shfl_xor(s1, 2); s2 += __shfl_xor(s2, 2);
    float mu = s1 * (1.f / 64.f);
    float var = s2 * (1.f / 64.f) - mu * mu;
    float inv = rsqrtf(var + 1e-5f);
    float* kdst = kn + ((size_t)(b * LQ + t) * NH + h) * DKH + q4 * 16;
#pragma unroll
    for (int i4 = 0; i4 < 4; i4++) {
      float4 c = {(vv[i4 * 4] - mu) * inv, (vv[i4 * 4 + 1] - mu) * inv,
                  (vv[i4 * 4 + 2] - mu) * inv, (vv[i4 * 4 + 3] - mu) * inv};
      *(float4*)(kdst + i4 * 4) = c;
    }
  }
  // ---- v: transpose to vt[b][h][d][t] ----
  {
    const size_t vrow = qrow + 2 * DH;
    float4 v0 = *(const float4*)(qkv + vrow);
    float4 v1 = *(const float4*)(qkv + vrow + 4);
    float4 v2 = *(const float4*)(qkv + vrow + 8);
    float4 v3 = *(const float4*)(qkv + vrow + 12);
    *(float4*)&Ls[r][q4 * 16] = v0;
    *(float4*)&Ls[r][q4 * 16 + 4] = v1;
    *(float4*)&Ls[r][q4 * 16 + 8] = v2;
    *(float4*)&Ls[r][q4 * 16 + 12] = v3;
  }
  __syncthreads();
  {
    const int dr = tid >> 2, tq = tid & 3;
    __hip_bfloat16 o[16];
#pragma unroll
    for (int i = 0; i < 16; i++) o[i] = __float2bfloat16(Ls[tq * 16 + i][dr]);
    __hip_bfloat16* dst = vt + ((size_t)bh * DKH + dr) * LQ + tc * 64 + tq * 16;
    *(uint4*)dst = *(uint4*)o;
    *(uint4*)(dst + 8) = *(uint4*)(o + 8);
  }
}

// ---------------- causal flash attention, bf16 MFMA ----------------
// grid (16 qtiles, NH, B), 256 threads = 4 waves x 16 Q-rows. K-tile 64.
// LDS K/V staged fragment-major: frag f=nt*2+kk at [(f*64+lane)*8] (lane-linear 16B).
__global__ __launch_bounds__(256) void attn_mfma_kernel(
    const __hip_bfloat16* __restrict__ qb, const __hip_bfloat16* __restrict__ kb,
    const __hip_bfloat16* __restrict__ vt, float* __restrict__ so) {
  const int it = 15 - blockIdx.x;           // heavy tiles first
  const int h = blockIdx.y, b = blockIdx.z;
  const int bh = b * NH + h;
  const int tid = threadIdx.x;
  const int w = tid >> 6, lane = tid & 63;
  const int l16 = lane & 15, quad = lane >> 4;
  __shared__ __attribute__((aligned(16))) __hip_bfloat16 Ks[8 * 64 * 8];
  __shared__ __attribute__((aligned(16))) __hip_bfloat16 Vs[8 * 64 * 8];
  __shared__ __attribute__((aligned(16))) __hip_bfloat16 Ps[4][2 * 64 * 8];
  const int i0 = it * 64;
  const int qrow = i0 + w * 16 + l16;
  bf16x8 aq[2];
  aq[0] = *(const bf16x8*)(qb + ((size_t)bh * LQ + qrow) * DKH + quad * 8);
  aq[1] = *(const bf16x8*)(qb + ((size_t)bh * LQ + qrow) * DKH + 32 + quad * 8);
  f32x4 o[4];
#pragma unroll
  for (int dt = 0; dt < 4; dt++) o[dt] = (f32x4){0.f, 0.f, 0.f, 0.f};
  float mrun[4], lrun[4];
#pragma unroll
  for (int r = 0; r < 4; r++) { mrun[r] = -3e38f; lrun[r] = 0.f; }
  const int mrow = i0 + w * 16 + quad * 4;  // +r = absolute Q row for C-layout

  for (int jt = 0; jt <= it; jt++) {
    const int j0 = jt * 64;
    __syncthreads();
#pragma unroll
    for (int ff = 0; ff < 2; ff++) {
      const int f = w * 2 + ff;
      const int nt = f >> 1, kk = f & 1;
      const __hip_bfloat16* gk = kb + ((size_t)bh * LQ + j0 + nt * 16 + l16) * DKH + kk * 32 + quad * 8;
      __builtin_amdgcn_global_load_lds((gas1_t)gk, (las3_t)(Ks + f * 512), 16, 0, 0);
      const __hip_bfloat16* gv = vt + ((size_t)bh * DKH + nt * 16 + l16) * LQ + j0 + kk * 32 + quad * 8;
      __builtin_amdgcn_global_load_lds((gas1_t)gv, (las3_t)(Vs + f * 512), 16, 0, 0);
    }
    __syncthreads();
    // S = Q*K^T (pre-scaled q)
    f32x4 s[4];
#pragma unroll
    for (int nt = 0; nt < 4; nt++) s[nt] = (f32x4){0.f, 0.f, 0.f, 0.f};
#pragma unroll
    for (int kk = 0; kk < 2; kk++)
#pragma unroll
      for (int nt = 0; nt < 4; nt++) {
        bf16x8 bk = *(const bf16x8*)(Ks + ((nt * 2 + kk) * 64 + lane) * 8);
        s[nt] = __builtin_amdgcn_mfma_f32_16x16x32_bf16(aq[kk], bk, s[nt], 0, 0, 0);
      }
    if (jt == it) {   // diagonal tile: causal mask
#pragma unroll
      for (int nt = 0; nt < 4; nt++)
#pragma unroll
        for (int r = 0; r < 4; r++)
          if (j0 + nt * 16 + l16 > mrow + r) s[nt][r] = -1e30f;
    }
    float mx[4], al[4], rs[4];
#pragma unroll
    for (int r = 0; r < 4; r++)
      mx[r] = fmaxf(fmaxf(s[0][r], s[1][r]), fmaxf(s[2][r], s[3][r]));
#pragma unroll
    for (int bit = 1; bit < 16; bit <<= 1)
#pragma unroll
      for (int r = 0; r < 4; r++) mx[r] = fmaxf(mx[r], __shfl_xor(mx[r], bit));
#pragma unroll
    for (int r = 0; r < 4; r++) {
      float mn = fmaxf(mrun[r], mx[r]);
      al[r] = __expf(mrun[r] - mn);
      mrun[r] = mn;
      rs[r] = 0.f;
    }
    // P = exp(S-m) -> LDS (C-layout -> A-fragment layout)
#pragma unroll
    for (int nt = 0; nt < 4; nt++) {
      const int kkp = nt >> 1;
      const int chunk = (nt * 2 + (l16 >> 3)) & 3;
#pragma unroll
      for (int r = 0; r < 4; r++) {
        float p = __expf(s[nt][r] - mrun[r]);
        rs[r] += p;
        Ps[w][(kkp * 64 + chunk * 16 + quad * 4 + r) * 8 + (l16 & 7)] = __float2bfloat16(p);
      }
    }
#pragma unroll
    for (int bit = 1; bit < 16; bit <<= 1)
#pragma unroll
      for (int r = 0; r < 4; r++) rs[r] += __shfl_xor(rs[r], bit);
#pragma unroll
    for (int r = 0; r < 4; r++) lrun[r] = lrun[r] * al[r] + rs[r];
#pragma unroll
    for (int dt = 0; dt < 4; dt++)
#pragma unroll
      for (int r = 0; r < 4; r++) o[dt][r] *= al[r];
    // O += P*V
#pragma unroll
    for (int kk = 0; kk < 2; kk++) {
      bf16x8 ap = *(const bf16x8*)(Ps[w] + (kk * 64 + lane) * 8);
#pragma unroll
      for (int dt = 0; dt < 4; dt++) {
        bf16x8 bv = *(const bf16x8*)(Vs + ((dt * 2 + kk) * 64 + lane) * 8);
        o[dt] = __builtin_amdgcn_mfma_f32_16x16x32_bf16(ap, bv, o[dt], 0, 0, 0);
      }
    }
  }
  float inv[4];
#pragma unroll
  for (int r = 0; r < 4; r++) inv[r] = 1.f / lrun[r];
#pragma unroll
  for (int dt = 0; dt < 4; dt++)
#pragma unroll
    for (int r = 0; r < 4; r++)
      so[((size_t)(b * LQ + mrow + r) * NH + h) * DKH + dt * 16 + l16] = o[dt][r] * inv[r];
}

// ============ chunked STP scan ============
__global__ __launch_bounds__(256) void state_kernel(
    const float* __restrict__ qkv, const float* __restrict__ kn,
    const float* __restrict__ ret_g, const float* __restrict__ co_g, float* __restrict__ S) {
  const int bh = blockIdx.x >> 1;
  const int half = blockIdx.x & 1;
  const int c = blockIdx.y;
  const int bb = bh >> 4, h = bh & 15;
  const int tid = threadIdx.x;
  const int dl = tid >> 3, j = tid & 7;
  const int d = half * 32 + dl;
  float F[8], R[8], Cc[8];
  const int base = h * 4096 + d * 64 + j * 8;
#pragma unroll
  for (int i = 0; i < 8; i++) {
    F[i] = 0.f;
    R[i] = ret_g[base + i];
    Cc[i] = co_g[base + i];
  }
  __shared__ float kb[2][8][64], vb[2][8][64];
  const int t00 = c * 64;
  {
    float ld[4];
#pragma unroll
    for (int i = 0; i < 4; i++) {
      int idx = tid + 256 * i;
      int which = idx >> 9, rem = idx & 511, s = rem >> 6, e = rem & 63;
      int t = t00 + s;
      if (which == 0) ld[i] = kn[((size_t)(bb * LQ + t) * NH + h) * DKH + e];
      else            ld[i] = qkv[((size_t)(bb * LQ + t) * 3 + 2) * DH + h * DKH + e];
    }
#pragma unroll
    for (int i = 0; i < 4; i++) {
      int idx = tid + 256 * i;
      int which = idx >> 9, rem = idx & 511, s = rem >> 6, e = rem & 63;
      if (which == 0) kb[0][s][e] = ld[i];
      else            vb[0][s][e] = ld[i];
    }
  }
  __syncthreads();
  for (int sc = 0; sc < 8; sc++) {
    const int p = sc & 1;
    float l2[4];
    if (sc < 7) {
      int t0 = t00 + (sc + 1) * 8;
#pragma unroll
      for (int i = 0; i < 4; i++) {
        int idx = tid + 256 * i;
        int which = idx >> 9, rem = idx & 511, s = rem >> 6, e = rem & 63;
        int t = t0 + s;
        if (which == 0) l2[i] = kn[((size_t)(bb * LQ + t) * NH + h) * DKH + e];
        else            l2[i] = qkv[((size_t)(bb * LQ + t) * 3 + 2) * DH + h * DKH + e];
      }
    }
#pragma unroll
    for (int s = 0; s < 8; s++) {
      float vd = vb[p][s][d];
#pragma unroll
      for (int i = 0; i < 8; i++) {
        float ke = kb[p][s][j * 8 + i];
        F[i] = fmaf(Cc[i] * vd, ke, R[i] * F[i]);
      }
    }
    if (sc < 7) {
      const int pn = p ^ 1;
#pragma unroll
      for (int i = 0; i < 4; i++) {
        int idx = tid + 256 * i;
        int which = idx >> 9, rem = idx & 511, s = rem >> 6, e = rem & 63;
        if (which == 0) kb[pn][s][e] = l2[i];
        else            vb[pn][s][e] = l2[i];
      }
    }
    __syncthreads();
  }
  const size_t sb = ((size_t)c * 2048 + ((size_t)bb * 16 + h) * 64 + d) * 64 + j * 8;
#pragma unroll
  for (int i = 0; i < 8; i++) S[sb + i] = F[i];
}

__global__ __launch_bounds__(256) void combine_kernel(
    const float* __restrict__ S, const float* __restrict__ ret64, float* __restrict__ Fs) {
  int n = blockIdx.x * 256 + threadIdx.x;
  float r64 = ret64[n & 65535];
  float F = 0.f;
  Fs[n] = 0.f;
#pragma unroll
  for (int c = 1; c < 16; c++) {
    F = fmaf(r64, F, S[(size_t)(c - 1) * 131072 + n]);
    Fs[(size_t)c * 131072 + n] = F;
  }
}

__global__ __launch_bounds__(256) void scan_out_kernel(
    const float* __restrict__ qkv, const float* __restrict__ kn, const float* __restrict__ W_LTM,
    const float* __restrict__ ret_g, const float* __restrict__ co_g, const float* __restrict__ Fs,
    float* __restrict__ stp) {
  const int bh = blockIdx.x >> 1;
  const int half = blockIdx.x & 1;
  const int c = blockIdx.y;
  const int bb = bh >> 4, h = bh & 15;
  const int tid = threadIdx.x;
  const int dl = tid >> 3, j = tid & 7;
  const int d = half * 32 + dl;
  float F[8], R[8], Cc[8], W[8];
  const int base = h * 4096 + d * 64 + j * 8;
  const size_t nbase = (size_t)c * 131072 + (((size_t)bb * 16 + h) * 64 + d) * 64 + j * 8;
#pragma unroll
  for (int i = 0; i < 8; i++) {
    F[i] = Fs[nbase + i];
    R[i] = ret_g[base + i];
    Cc[i] = co_g[base + i];
    W[i] = W_LTM[base + i];
  }
  __shared__ float qb[2][8][64], kb[2][8][64], vb[2][8][64];
  const int t00 = c * 64;
  {
    float ld[6];
#pragma unroll
    for (int i = 0; i < 6; i++) {
      int idx = tid + 256 * i;
      int which = idx >> 9, rem = idx & 511, s = rem >> 6, e = rem & 63;
      int t = t00 + s;
      if (which == 0)      ld[i] = qkv[((size_t)(bb * LQ + t) * 3 + 0) * DH + h * DKH + e];
      else if (which == 1) ld[i] = kn[((size_t)(bb * LQ + t) * NH + h) * DKH + e];
      else                 ld[i] = qkv[((size_t)(bb * LQ + t) * 3 + 2) * DH + h * DKH + e];
    }
#pragma unroll
    for (int i = 0; i < 6; i++) {
      int idx = tid + 256 * i;
      int which = idx >> 9, rem = idx & 511, s = rem >> 6, e = rem & 63;
      if (which == 0) qb[0][s][e] = ld[i];
      else if (which == 1) kb[0][s][e] = ld[i];
      else vb[0][s][e] = ld[i];
    }
  }
  __syncthreads();
  for (int sc = 0; sc < 8; sc++) {
    const int p = sc & 1;
    float l2[6];
    if (sc < 7) {
      int t0 = t00 + (sc + 1) * 8;
#pragma unroll
      for (int i = 0; i < 6; i++) {
        int idx = tid + 256 * i;
        int which = idx >> 9, rem = idx & 511, s = rem >> 6, e = rem & 63;
        int t = t0 + s;
        if (which == 0)      l2[i] = qkv[((size_t)(bb * LQ + t) * 3 + 0) * DH + h * DKH + e];
        else if (which == 1) l2[i] = kn[((size_t)(bb * LQ + t) * NH + h) * DKH + e];
        else                 l2[i] = qkv[((size_t)(bb * LQ + t) * 3 + 2) * DH + h * DKH + e];
      }
    }
#pragma unroll
    for (int s = 0; s < 8; s++) {
      float vd = vb[p][s][d];
      float yp = 0.f;
#pragma unroll
      for (int i = 0; i < 8; i++) {
        float ke = kb[p][s][j * 8 + i];
        F[i] = fmaf(Cc[i] * vd, ke, R[i] * F[i]);
        yp = fmaf(W[i] + F[i], qb[p][s][j * 8 + i], yp);
      }
      yp += __shfl_xor(yp, 1);
      yp += __shfl_xor(yp, 2);
      yp += __shfl_xor(yp, 4);
      if (j == 0) stp[((size_t)(bb * LQ + t00 + sc * 8 + s) * NH + h) * DKH + d] = yp;
    }
    if (sc < 7) {
      const int pn = p ^ 1;
#pragma unroll
      for (int i = 0; i < 6; i++) {
        int idx = tid + 256 * i;
        int which = idx >> 9, rem = idx & 511, s = rem >> 6, e = rem & 63;
        if (which == 0) qb[pn][s][e] = l2[i];
        else if (which == 1) kb[pn][s][e] = l2[i];
        else vb[pn][s][e] = l2[i];
      }
    }
    __syncthreads();
  }
}

extern "C" void kernel_launch(void* const* d_in, const int* in_sizes, int n_in,
                              void* d_out, int out_size, void* d_ws, size_t ws_size,
                              hipStream_t stream) {
  (void)in_sizes; (void)n_in; (void)out_size; (void)ws_size;
  const float* x        = (const float*)d_in[0];
  const float* W_qkv    = (const float*)d_in[1];
  const float* W_o      = (const float*)d_in[2];
  const float* W_LTM    = (const float*)d_in[3];
  const float* V_gs     = (const float*)d_in[4];
  const float* V_T0     = (const float*)d_in[5];
  const float* beta_tau = (const float*)d_in[6];
  const float* beta_gm  = (const float*)d_in[7];
  const float* C_ch     = (const float*)d_in[8];
  const float* gamma_   = (const float*)d_in[9];
  const float* alpha_p  = (const float*)d_in[10];
  const float* IC_thr   = (const float*)d_in[11];
  const float* gate     = (const float*)d_in[12];

  float* ws  = (float*)d_ws;
  float* qkv   = ws;                    // 6291456 f32
  float* kn    = qkv + 6291456;         // 2097152 f32
  float* so    = kn + 2097152;          // 2097152 f32
  float* stp   = so + 2097152;          // 2097152 f32 (8 MB)
  float* ret   = stp + 2097152;
  float* ret64 = ret + 65536;
  float* co    = ret64 + 65536;
  float* g     = co + 65536;            // 64
  __hip_bfloat16* xb  = (__hip_bfloat16*)(g + 64);   // 2097152 bf16
  __hip_bfloat16* wot = xb + 2097152;                // 1048576 bf16
  float* Sbuf = (float*)(wot + 1048576);             // 1966080 f32
  float* Fs   = Sbuf + 1966080;                      // 2097152 f32
  __hip_bfloat16* qbb = (__hip_bfloat16*)(Fs + 2097152);  // 2097152 bf16
  __hip_bfloat16* kbb = qbb + 2097152;                    // 2097152 bf16
  __hip_bfloat16* vtb = kbb + 2097152;                    // 2097152 bf16
  __hip_bfloat16* mixb = xb;                          // alias: xb dead after qkv GEMM
  __hip_bfloat16* wqt  = (__hip_bfloat16*)stp;        // alias: stp written only in scan pass 3
  float* out = (float*)d_out;

  physics_kernel<<<256, 256, 0, stream>>>(W_LTM, V_gs, V_T0, beta_tau, beta_gm, C_ch,
                                          gamma_, alpha_p, IC_thr, gate, ret, ret64, co, g);
  cvt_kernel<<<2048, 256, 0, stream>>>(x, xb);
  tcvt_kernel<<<dim3(96, 32), 256, 0, stream>>>(W_qkv, wqt, 1024, 3072);
  tcvt_kernel<<<dim3(32, 32), 256, 0, stream>>>(W_o, wot, 1024, 1024);
  gemm_bt_kernel<<<dim3(24, 16), 256, 0, stream>>>(xb, wqt, qkv, 2048, 3072, 1024);
  cvt_qkv_kernel<<<dim3(16, 16, 2), 256, 0, stream>>>(qkv, qbb, kbb, vtb, kn);
  attn_mfma_kernel<<<dim3(16, 16, 2), 256, 0, stream>>>(qbb, kbb, vtb, so);
  state_kernel<<<dim3(64, 15), 256, 0, stream>>>(qkv, kn, ret, co, Sbuf);
  combine_kernel<<<512, 256, 0, stream>>>(Sbuf, ret64, Fs);
  scan_out_kernel<<<dim3(64, 16), 256, 0, stream>>>(qkv, kn, W_LTM, ret, co, Fs, stp);
  mix_kernel<<<2048, 256, 0, stream>>>(so, stp, g, mixb);
  gemm_bt_kernel<<<dim3(8, 16), 256, 0, stream>>>(mixb, wot, out, 2048, 1024, 1024);
}

// Round 5
// 241.022 us; speedup vs baseline: 3.5851x; 1.0517x over previous
//
#include <hip/hip_runtime.h>
#include <hip/hip_bf16.h>
#include <math.h>

#define LQ 1024
#define DH 1024
#define NH 16
#define DKH 64

typedef __bf16 bf16x8 __attribute__((ext_vector_type(8)));
typedef float f32x4 __attribute__((ext_vector_type(4)));
typedef const unsigned int __attribute__((address_space(1)))* gas1_t;
typedef unsigned int __attribute__((address_space(3)))* las3_t;

__device__ __forceinline__ unsigned pack2bf(float a, float b) {
  union { __hip_bfloat16 h[2]; unsigned u; } t;
  t.h[0] = __float2bfloat16(a);
  t.h[1] = __float2bfloat16(b);
  return t.u;
}
__device__ __forceinline__ void store_c(float* p, float v) { *p = v; }
__device__ __forceinline__ void store_c(__hip_bfloat16* p, float v) { *p = __float2bfloat16(v); }

// ---------------- physics precompute ----------------
__global__ __launch_bounds__(256) void physics_kernel(
    const float* __restrict__ W_LTM, const float* __restrict__ V_gs, const float* __restrict__ V_T0,
    const float* __restrict__ beta_tau, const float* __restrict__ beta_gm, const float* __restrict__ C_ch,
    const float* __restrict__ gamma_, const float* __restrict__ alpha_ppd, const float* __restrict__ IC_thr,
    const float* __restrict__ gate, float* __restrict__ ret, float* __restrict__ ret64,
    float* __restrict__ co, float* __restrict__ g_out) {
  int idx = blockIdx.x * 256 + threadIdx.x;
  int h = idx >> 12;
  float w = W_LTM[idx];
  float veff = V_gs[h] - V_T0[h] + w;
  float sp = fmaxf(veff, 0.f) + log1pf(expf(-fabsf(veff)));
  float gch = beta_tau[h] * sp;
  float e1 = gch / C_ch[h];
  float retv = expf(-e1);
  float sig = 1.f / (1.f + expf(-veff));
  float G = beta_gm[h] * sp * sig;
  float sm = tanhf(alpha_ppd[0] * (gch - IC_thr[0]));
  ret[idx] = retv;
  ret64[idx] = expf(-64.f * e1);
  co[idx] = gamma_[h] * sm * G;
  if (idx < NH) g_out[idx] = 1.f / (1.f + expf(-gate[idx]));
}

// ---------------- fp32 -> bf16 elementwise (x) ----------------
__global__ __launch_bounds__(256) void cvt_kernel(const float* __restrict__ in, __hip_bfloat16* __restrict__ out) {
  size_t i = (size_t)(blockIdx.x * 256 + threadIdx.x) * 4;
  float4 v = *(const float4*)(in + i);
  __hip_bfloat16 t[4] = {__float2bfloat16(v.x), __float2bfloat16(v.y),
                         __float2bfloat16(v.z), __float2bfloat16(v.w)};
  *(uint2*)(out + i) = *(uint2*)t;
}

// ---------------- fp32 [K][N] -> bf16 [N][K] transpose-convert ----------------
__global__ __launch_bounds__(256) void tcvt_kernel(const float* __restrict__ W, __hip_bfloat16* __restrict__ Wt,
                                                   int K, int N) {
  __shared__ float t[32][33];
  int n0 = blockIdx.x * 32, k0 = blockIdx.y * 32;
  int r = threadIdx.x >> 5, c = threadIdx.x & 31;
#pragma unroll
  for (int i = 0; i < 4; i++) t[r + 8 * i][c] = W[(size_t)(k0 + r + 8 * i) * N + n0 + c];
  __syncthreads();
#pragma unroll
  for (int i = 0; i < 4; i++)
    Wt[(size_t)(n0 + r + 8 * i) * K + k0 + c] = __float2bfloat16(t[c][r + 8 * i]);
}

// ---------------- gate mix -> bf16 ----------------
__global__ __launch_bounds__(256) void mix_kernel(const float* __restrict__ so, const float* __restrict__ stp,
                                                  const float* __restrict__ g, __hip_bfloat16* __restrict__ out) {
  size_t base = (size_t)(blockIdx.x * 256 + threadIdx.x) * 4;
  float gv = g[(base >> 6) & 15];
  float4 a = *(const float4*)(so + base);
  float4 b = *(const float4*)(stp + base);
  __hip_bfloat16 t[4] = {__float2bfloat16(gv * a.x + (1.f - gv) * b.x),
                         __float2bfloat16(gv * a.y + (1.f - gv) * b.y),
                         __float2bfloat16(gv * a.z + (1.f - gv) * b.z),
                         __float2bfloat16(gv * a.w + (1.f - gv) * b.w)};
  *(uint2*)(out + base) = *(uint2*)t;
}

// ---------------- bf16 MFMA GEMM: C[M,N] = A[M,K] * Bt[N,K]^T, OT output ----------------
template <typename OT>
__global__ __launch_bounds__(256) void gemm_bt_kernel(
    const __hip_bfloat16* __restrict__ A, const __hip_bfloat16* __restrict__ Bt,
    OT* __restrict__ C, int M, int N, int K) {
  __shared__ unsigned short As[128 * 32];
  __shared__ unsigned short Bs[128 * 32];
  const int tid = threadIdx.x;
  const int w = tid >> 6, lane = tid & 63;
  const int quad = lane >> 4, l16 = lane & 15;
  const int wm = w & 1, wn = w >> 1;
  const int row0 = blockIdx.y * 128, col0 = blockIdx.x * 128;
  const int sr = lane >> 2;
  const int sk = (lane & 3) * 8;
  f32x4 acc[4][4];
#pragma unroll
  for (int i = 0; i < 4; i++)
#pragma unroll
    for (int j = 0; j < 4; j++) acc[i][j] = (f32x4){0.f, 0.f, 0.f, 0.f};

  for (int k0 = 0; k0 < K; k0 += 32) {
    __syncthreads();
#pragma unroll
    for (int c = 0; c < 2; c++) {
      int s = c * 4 + w;
      const __hip_bfloat16* gA = A + (size_t)(row0 + s * 16 + sr) * K + k0 + sk;
      __builtin_amdgcn_global_load_lds((gas1_t)gA, (las3_t)((char*)As + s * 1024), 16, 0, 0);
      const __hip_bfloat16* gB = Bt + (size_t)(col0 + s * 16 + sr) * K + k0 + sk;
      __builtin_amdgcn_global_load_lds((gas1_t)gB, (las3_t)((char*)Bs + s * 1024), 16, 0, 0);
    }
    __syncthreads();
    bf16x8 af[4], bfr[4];
#pragma unroll
    for (int i = 0; i < 4; i++)
      af[i] = *(const bf16x8*)((const char*)As + (((wm * 64 + i * 16 + l16) * 32 + quad * 8) << 1));
#pragma unroll
    for (int j = 0; j < 4; j++)
      bfr[j] = *(const bf16x8*)((const char*)Bs + (((wn * 64 + j * 16 + l16) * 32 + quad * 8) << 1));
#pragma unroll
    for (int i = 0; i < 4; i++)
#pragma unroll
      for (int j = 0; j < 4; j++)
        acc[i][j] = __builtin_amdgcn_mfma_f32_16x16x32_bf16(af[i], bfr[j], acc[i][j], 0, 0, 0);
  }
#pragma unroll
  for (int i = 0; i < 4; i++) {
    int rowb = row0 + wm * 64 + i * 16 + quad * 4;
#pragma unroll
    for (int j = 0; j < 4; j++) {
      int col = col0 + wn * 64 + j * 16 + l16;
#pragma unroll
      for (int r = 0; r < 4; r++)
        store_c(&C[(size_t)(rowb + r) * N + col], acc[i][j][r]);
    }
  }
}

// ---------------- LN(k)->kn fp32, transpose v->vt bf16 (from bf16 qkv) ----------------
__global__ __launch_bounds__(256) void cvt_qkv_kernel(
    const __hip_bfloat16* __restrict__ qkvb, __hip_bfloat16* __restrict__ vt, float* __restrict__ kn) {
  const int tc = blockIdx.x, h = blockIdx.y, b = blockIdx.z;
  const int bh = b * NH + h;
  const int tid = threadIdx.x;
  const int r = tid >> 2;        // local t 0..63
  const int q4 = tid & 3;        // d quarter (16)
  const int t = tc * 64 + r;
  __shared__ float Ls[64][65];
  const size_t rowbase = (size_t)(b * LQ + t) * 3 * DH + h * DKH + q4 * 16;

  // ---- k: LayerNorm fp32 ----
  {
    bf16x8 k0 = *(const bf16x8*)(qkvb + rowbase + DH);
    bf16x8 k1 = *(const bf16x8*)(qkvb + rowbase + DH + 8);
    float vv[16];
#pragma unroll
    for (int i = 0; i < 8; i++) { vv[i] = (float)k0[i]; vv[8 + i] = (float)k1[i]; }
    float s1 = 0.f, s2 = 0.f;
#pragma unroll
    for (int i = 0; i < 16; i++) { s1 += vv[i]; s2 += vv[i] * vv[i]; }
    s1 += __shfl_xor(s1, 1); s2 += __shfl_xor(s2, 1);
    s1 += __shfl_xor(s1, 2); s2 += __shfl_xor(s2, 2);
    float mu = s1 * (1.f / 64.f);
    float var = s2 * (1.f / 64.f) - mu * mu;
    float inv = rsqrtf(var + 1e-5f);
    float* kdst = kn + ((size_t)(b * LQ + t) * NH + h) * DKH + q4 * 16;
#pragma unroll
    for (int i4 = 0; i4 < 4; i4++) {
      float4 c = {(vv[i4 * 4] - mu) * inv, (vv[i4 * 4 + 1] - mu) * inv,
                  (vv[i4 * 4 + 2] - mu) * inv, (vv[i4 * 4 + 3] - mu) * inv};
      *(float4*)(kdst + i4 * 4) = c;
    }
  }
  // ---- v: transpose to vt[bh][d][t] ----
  {
    bf16x8 v0 = *(const bf16x8*)(qkvb + rowbase + 2 * DH);
    bf16x8 v1 = *(const bf16x8*)(qkvb + rowbase + 2 * DH + 8);
#pragma unroll
    for (int i = 0; i < 8; i++) {
      Ls[r][q4 * 16 + i] = (float)v0[i];
      Ls[r][q4 * 16 + 8 + i] = (float)v1[i];
    }
  }
  __syncthreads();
  {
    const int dr = tid >> 2, tq = tid & 3;
    __hip_bfloat16 o[16];
#pragma unroll
    for (int i = 0; i < 16; i++) o[i] = __float2bfloat16(Ls[tq * 16 + i][dr]);
    __hip_bfloat16* dst = vt + ((size_t)bh * DKH + dr) * LQ + tc * 64 + tq * 16;
    *(uint4*)dst = *(uint4*)o;
    *(uint4*)(dst + 8) = *(uint4*)(o + 8);
  }
}

// ---------------- causal flash attention, bf16 MFMA, S^T trick (no P LDS transit) ----------------
// grid (16, NH, B), 256 thr = 4 waves x 16 q-rows. K-tile 64.
// S^T = mfma(Kfrag, Qfrag): lane owns q=l16, keys quad*4+r per 16-tile.
// P exchange: cross-quad ds_bpermute among lanes {l16, l16+16, l16+32, l16+48}.
// O^T = mfma(Vtfrag, Pfrag): lane owns q=l16, d = dt*16+quad*4+r -> float4 stores.
__global__ __launch_bounds__(256) void attn_mfma_kernel(
    const __hip_bfloat16* __restrict__ qkvb, const __hip_bfloat16* __restrict__ vt,
    float* __restrict__ so) {
  const int it = 15 - blockIdx.x;           // heavy tiles first
  const int h = blockIdx.y, b = blockIdx.z;
  const int bh = b * NH + h;
  const int tid = threadIdx.x;
  const int w = tid >> 6, lane = tid & 63;
  const int l16 = lane & 15, quad = lane >> 4;
  __shared__ __attribute__((aligned(16))) __hip_bfloat16 Ks[8 * 64 * 8];
  __shared__ __attribute__((aligned(16))) __hip_bfloat16 Vs[8 * 64 * 8];
  const int i0 = it * 64;
  const int q_abs = i0 + w * 16 + l16;
  bf16x8 aq[2];
  aq[0] = *(const bf16x8*)(qkvb + (size_t)(b * LQ + q_abs) * 3 * DH + h * DKH + quad * 8);
  aq[1] = *(const bf16x8*)(qkvb + (size_t)(b * LQ + q_abs) * 3 * DH + h * DKH + 32 + quad * 8);
  f32x4 o[4];
#pragma unroll
  for (int dt = 0; dt < 4; dt++) o[dt] = (f32x4){0.f, 0.f, 0.f, 0.f};
  float mrun = -3e38f, lrun = 0.f;

  for (int jt = 0; jt <= it; jt++) {
    const int j0 = jt * 64;
    __syncthreads();
#pragma unroll
    for (int ff = 0; ff < 2; ff++) {
      const int f = w * 2 + ff;
      const int nt = f >> 1, kk = f & 1;
      const __hip_bfloat16* gk = qkvb + (size_t)(b * LQ + j0 + nt * 16 + l16) * 3 * DH + DH +
                                 h * DKH + kk * 32 + quad * 8;
      __builtin_amdgcn_global_load_lds((gas1_t)gk, (las3_t)(Ks + f * 512), 16, 0, 0);
      const __hip_bfloat16* gv = vt + ((size_t)bh * DKH + nt * 16 + l16) * LQ + j0 + kk * 32 + quad * 8;
      __builtin_amdgcn_global_load_lds((gas1_t)gv, (las3_t)(Vs + f * 512), 16, 0, 0);
    }
    __syncthreads();
    // S^T: s[nt][r] = S[q=l16][key = j0 + nt*16 + quad*4 + r]
    f32x4 s[4];
#pragma unroll
    for (int nt = 0; nt < 4; nt++) s[nt] = (f32x4){0.f, 0.f, 0.f, 0.f};
#pragma unroll
    for (int kk = 0; kk < 2; kk++)
#pragma unroll
      for (int nt = 0; nt < 4; nt++) {
        bf16x8 bk = *(const bf16x8*)(Ks + ((nt * 2 + kk) * 64 + lane) * 8);
        s[nt] = __builtin_amdgcn_mfma_f32_16x16x32_bf16(bk, aq[kk], s[nt], 0, 0, 0);
      }
    // scale + causal mask (diagonal tile only)
#pragma unroll
    for (int nt = 0; nt < 4; nt++)
#pragma unroll
      for (int r = 0; r < 4; r++) {
        float sv = s[nt][r] * 0.125f;
        if (jt == it && (j0 + nt * 16 + quad * 4 + r > q_abs)) sv = -1e30f;
        s[nt][r] = sv;
      }
    // online softmax: per-lane stats for q=l16, reduce across quads
    float mx = -3e38f;
#pragma unroll
    for (int nt = 0; nt < 4; nt++)
#pragma unroll
      for (int r = 0; r < 4; r++) mx = fmaxf(mx, s[nt][r]);
    mx = fmaxf(mx, __shfl_xor(mx, 16));
    mx = fmaxf(mx, __shfl_xor(mx, 32));
    float mn = fmaxf(mrun, mx);
    float al = __expf(mrun - mn);
    mrun = mn;
    float p[4][4];
    float rs = 0.f;
#pragma unroll
    for (int nt = 0; nt < 4; nt++)
#pragma unroll
      for (int r = 0; r < 4; r++) {
        float pv = __expf(s[nt][r] - mn);
        p[nt][r] = pv;
        rs += pv;
      }
    rs += __shfl_xor(rs, 16);
    rs += __shfl_xor(rs, 32);
    lrun = lrun * al + rs;
    // pack p -> bf16 dword pairs
    unsigned pk[4][2];
#pragma unroll
    for (int nt = 0; nt < 4; nt++) {
      pk[nt][0] = pack2bf(p[nt][0], p[nt][1]);
      pk[nt][1] = pack2bf(p[nt][2], p[nt][3]);
    }
    // cross-quad exchange: build P B-operand frags
    const int srcA = l16 | ((quad & 1) << 5);
    const bool hi_sel = (quad >> 1) != 0;
    bf16x8 ap[2];
#pragma unroll
    for (int kk = 0; kk < 2; kk++) {
      union { unsigned u[4]; bf16x8 v; } cv;
#pragma unroll
      for (int g = 0; g < 2; g++) {
        int src = srcA + (g << 4);
        unsigned lo0 = (unsigned)__shfl((int)pk[kk * 2][0], src);
        unsigned lo1 = (unsigned)__shfl((int)pk[kk * 2][1], src);
        unsigned hi0 = (unsigned)__shfl((int)pk[kk * 2 + 1][0], src);
        unsigned hi1 = (unsigned)__shfl((int)pk[kk * 2 + 1][1], src);
        cv.u[g * 2] = hi_sel ? hi0 : lo0;
        cv.u[g * 2 + 1] = hi_sel ? hi1 : lo1;
      }
      ap[kk] = cv.v;
    }
    // O^T rescale + accumulate
#pragma unroll
    for (int dt = 0; dt < 4; dt++)
#pragma unroll
      for (int r = 0; r < 4; r++) o[dt][r] *= al;
#pragma unroll
    for (int kk = 0; kk < 2; kk++)
#pragma unroll
      for (int dt = 0; dt < 4; dt++) {
        bf16x8 bv = *(const bf16x8*)(Vs + ((dt * 2 + kk) * 64 + lane) * 8);
        o[dt] = __builtin_amdgcn_mfma_f32_16x16x32_bf16(bv, ap[kk], o[dt], 0, 0, 0);
      }
  }
  float inv = 1.f / lrun;
  float* ob = so + ((size_t)(b * LQ + q_abs) * NH + h) * DKH + quad * 4;
#pragma unroll
  for (int dt = 0; dt < 4; dt++) {
    float4 c = {o[dt][0] * inv, o[dt][1] * inv, o[dt][2] * inv, o[dt][3] * inv};
    *(float4*)(ob + dt * 16) = c;
  }
}

// ============ chunked STP scan (q/v from bf16 qkv, kn fp32) ============
__global__ __launch_bounds__(256) void state_kernel(
    const __hip_bfloat16* __restrict__ qkvb, const float* __restrict__ kn,
    const float* __restrict__ ret_g, const float* __restrict__ co_g, float* __restrict__ S) {
  const int bh = blockIdx.x >> 1;
  const int half = blockIdx.x & 1;
  const int c = blockIdx.y;
  const int bb = bh >> 4, h = bh & 15;
  const int tid = threadIdx.x;
  const int dl = tid >> 3, j = tid & 7;
  const int d = half * 32 + dl;
  float F[8], R[8], Cc[8];
  const int base = h * 4096 + d * 64 + j * 8;
#pragma unroll
  for (int i = 0; i < 8; i++) {
    F[i] = 0.f;
    R[i] = ret_g[base + i];
    Cc[i] = co_g[base + i];
  }
  __shared__ float kb[2][8][64], vb[2][8][64];
  const int t00 = c * 64;
  {
    float ld[4];
#pragma unroll
    for (int i = 0; i < 4; i++) {
      int idx = tid + 256 * i;
      int which = idx >> 9, rem = idx & 511, s = rem >> 6, e = rem & 63;
      int t = t00 + s;
      if (which == 0) ld[i] = kn[((size_t)(bb * LQ + t) * NH + h) * DKH + e];
      else            ld[i] = __bfloat162float(qkvb[((size_t)(bb * LQ + t) * 3 + 2) * DH + h * DKH + e]);
    }
#pragma unroll
    for (int i = 0; i < 4; i++) {
      int idx = tid + 256 * i;
      int which = idx >> 9, rem = idx & 511, s = rem >> 6, e = rem & 63;
      if (which == 0) kb[0][s][e] = ld[i];
      else            vb[0][s][e] = ld[i];
    }
  }
  __syncthreads();
  for (int sc = 0; sc < 8; sc++) {
    const int p = sc & 1;
    float l2[4];
    if (sc < 7) {
      int t0 = t00 + (sc + 1) * 8;
#pragma unroll
      for (int i = 0; i < 4; i++) {
        int idx = tid + 256 * i;
        int which = idx >> 9, rem = idx & 511, s = rem >> 6, e = rem & 63;
        int t = t0 + s;
        if (which == 0) l2[i] = kn[((size_t)(bb * LQ + t) * NH + h) * DKH + e];
        else            l2[i] = __bfloat162float(qkvb[((size_t)(bb * LQ + t) * 3 + 2) * DH + h * DKH + e]);
      }
    }
#pragma unroll
    for (int s = 0; s < 8; s++) {
      float vd = vb[p][s][d];
#pragma unroll
      for (int i = 0; i < 8; i++) {
        float ke = kb[p][s][j * 8 + i];
        F[i] = fmaf(Cc[i] * vd, ke, R[i] * F[i]);
      }
    }
    if (sc < 7) {
      const int pn = p ^ 1;
#pragma unroll
      for (int i = 0; i < 4; i++) {
        int idx = tid + 256 * i;
        int which = idx >> 9, rem = idx & 511, s = rem >> 6, e = rem & 63;
        if (which == 0) kb[pn][s][e] = l2[i];
        else            vb[pn][s][e] = l2[i];
      }
    }
    __syncthreads();
  }
  const size_t sb = ((size_t)c * 2048 + ((size_t)bb * 16 + h) * 64 + d) * 64 + j * 8;
#pragma unroll
  for (int i = 0; i < 8; i++) S[sb + i] = F[i];
}

__global__ __launch_bounds__(256) void combine_kernel(
    const float* __restrict__ S, const float* __restrict__ ret64, float* __restrict__ Fs) {
  int n = blockIdx.x * 256 + threadIdx.x;
  float r64 = ret64[n & 65535];
  float F = 0.f;
  Fs[n] = 0.f;
#pragma unroll
  for (int c = 1; c < 16; c++) {
    F = fmaf(r64, F, S[(size_t)(c - 1) * 131072 + n]);
    Fs[(size_t)c * 131072 + n] = F;
  }
}

__global__ __launch_bounds__(256) void scan_out_kernel(
    const __hip_bfloat16* __restrict__ qkvb, const float* __restrict__ kn, const float* __restrict__ W_LTM,
    const float* __restrict__ ret_g, const float* __restrict__ co_g, const float* __restrict__ Fs,
    float* __restrict__ stp) {
  const int bh = blockIdx.x >> 1;
  const int half = blockIdx.x & 1;
  const int c = blockIdx.y;
  const int bb = bh >> 4, h = bh & 15;
  const int tid = threadIdx.x;
  const int dl = tid >> 3, j = tid & 7;
  const int d = half * 32 + dl;
  float F[8], R[8], Cc[8], W[8];
  const int base = h * 4096 + d * 64 + j * 8;
  const size_t nbase = (size_t)c * 131072 + (((size_t)bb * 16 + h) * 64 + d) * 64 + j * 8;
#pragma unroll
  for (int i = 0; i < 8; i++) {
    F[i] = Fs[nbase + i];
    R[i] = ret_g[base + i];
    Cc[i] = co_g[base + i];
    W[i] = W_LTM[base + i];
  }
  __shared__ float qb[2][8][64], kb[2][8][64], vb[2][8][64];
  const int t00 = c * 64;
  {
    float ld[6];
#pragma unroll
    for (int i = 0; i < 6; i++) {
      int idx = tid + 256 * i;
      int which = idx >> 9, rem = idx & 511, s = rem >> 6, e = rem & 63;
      int t = t00 + s;
      if (which == 0)      ld[i] = __bfloat162float(qkvb[((size_t)(bb * LQ + t) * 3 + 0) * DH + h * DKH + e]);
      else if (which == 1) ld[i] = kn[((size_t)(bb * LQ + t) * NH + h) * DKH + e];
      else                 ld[i] = __bfloat162float(qkvb[((size_t)(bb * LQ + t) * 3 + 2) * DH + h * DKH + e]);
    }
#pragma unroll
    for (int i = 0; i < 6; i++) {
      int idx = tid + 256 * i;
      int which = idx >> 9, rem = idx & 511, s = rem >> 6, e = rem & 63;
      if (which == 0) qb[0][s][e] = ld[i];
      else if (which == 1) kb[0][s][e] = ld[i];
      else vb[0][s][e] = ld[i];
    }
  }
  __syncthreads();
  for (int sc = 0; sc < 8; sc++) {
    const int p = sc & 1;
    float l2[6];
    if (sc < 7) {
      int t0 = t00 + (sc + 1) * 8;
#pragma unroll
      for (int i = 0; i < 6; i++) {
        int idx = tid + 256 * i;
        int which = idx >> 9, rem = idx & 511, s = rem >> 6, e = rem & 63;
        int t = t0 + s;
        if (which == 0)      l2[i] = __bfloat162float(qkvb[((size_t)(bb * LQ + t) * 3 + 0) * DH + h * DKH + e]);
        else if (which == 1) l2[i] = kn[((size_t)(bb * LQ + t) * NH + h) * DKH + e];
        else                 l2[i] = __bfloat162float(qkvb[((size_t)(bb * LQ + t) * 3 + 2) * DH + h * DKH + e]);
      }
    }
#pragma unroll
    for (int s = 0; s < 8; s++) {
      float vd = vb[p][s][d];
      float yp = 0.f;
#pragma unroll
      for (int i = 0; i < 8; i++) {
        float ke = kb[p][s][j * 8 + i];
        F[i] = fmaf(Cc[i] * vd, ke, R[i] * F[i]);
        yp = fmaf(W[i] + F[i], qb[p][s][j * 8 + i], yp);
      }
      yp += __shfl_xor(yp, 1);
      yp += __shfl_xor(yp, 2);
      yp += __shfl_xor(yp, 4);
      if (j == 0) stp[((size_t)(bb * LQ + t00 + sc * 8 + s) * NH + h) * DKH + d] = yp;
    }
    if (sc < 7) {
      const int pn = p ^ 1;
#pragma unroll
      for (int i = 0; i < 6; i++) {
        int idx = tid + 256 * i;
        int which = idx >> 9, rem = idx & 511, s = rem >> 6, e = rem & 63;
        if (which == 0) qb[pn][s][e] = l2[i];
        else if (which == 1) kb[pn][s][e] = l2[i];
        else vb[pn][s][e] = l2[i];
      }
    }
    __syncthreads();
  }
}

extern "C" void kernel_launch(void* const* d_in, const int* in_sizes, int n_in,
                              void* d_out, int out_size, void* d_ws, size_t ws_size,
                              hipStream_t stream) {
  (void)in_sizes; (void)n_in; (void)out_size; (void)ws_size;
  const float* x        = (const float*)d_in[0];
  const float* W_qkv    = (const float*)d_in[1];
  const float* W_o      = (const float*)d_in[2];
  const float* W_LTM    = (const float*)d_in[3];
  const float* V_gs     = (const float*)d_in[4];
  const float* V_T0     = (const float*)d_in[5];
  const float* beta_tau = (const float*)d_in[6];
  const float* beta_gm  = (const float*)d_in[7];
  const float* C_ch     = (const float*)d_in[8];
  const float* gamma_   = (const float*)d_in[9];
  const float* alpha_p  = (const float*)d_in[10];
  const float* IC_thr   = (const float*)d_in[11];
  const float* gate     = (const float*)d_in[12];

  float* ws  = (float*)d_ws;
  __hip_bfloat16* qkvb = (__hip_bfloat16*)ws;        // 6291456 bf16 (3145728 f32 slots)
  float* kn    = ws + 3145728;          // 2097152 f32
  float* so    = kn + 2097152;          // 2097152 f32
  float* stp   = so + 2097152;          // 2097152 f32 (8 MB)
  float* ret   = stp + 2097152;
  float* ret64 = ret + 65536;
  float* co    = ret64 + 65536;
  float* g     = co + 65536;            // 64
  __hip_bfloat16* xb  = (__hip_bfloat16*)(g + 64);   // 2097152 bf16
  __hip_bfloat16* wot = xb + 2097152;                // 1048576 bf16
  float* Sbuf = (float*)(wot + 1048576);             // 1966080 f32
  float* Fs   = Sbuf + 1966080;                      // 2097152 f32
  __hip_bfloat16* vtb = (__hip_bfloat16*)(Fs + 2097152);  // 2097152 bf16
  __hip_bfloat16* mixb = xb;                          // alias: xb dead after qkv GEMM
  __hip_bfloat16* wqt  = (__hip_bfloat16*)stp;        // alias: stp written only in scan pass 3
  float* out = (float*)d_out;

  physics_kernel<<<256, 256, 0, stream>>>(W_LTM, V_gs, V_T0, beta_tau, beta_gm, C_ch,
                                          gamma_, alpha_p, IC_thr, gate, ret, ret64, co, g);
  cvt_kernel<<<2048, 256, 0, stream>>>(x, xb);
  tcvt_kernel<<<dim3(96, 32), 256, 0, stream>>>(W_qkv, wqt, 1024, 3072);
  tcvt_kernel<<<dim3(32, 32), 256, 0, stream>>>(W_o, wot, 1024, 1024);
  gemm_bt_kernel<__hip_bfloat16><<<dim3(24, 16), 256, 0, stream>>>(xb, wqt, qkvb, 2048, 3072, 1024);
  cvt_qkv_kernel<<<dim3(16, 16, 2), 256, 0, stream>>>(qkvb, vtb, kn);
  attn_mfma_kernel<<<dim3(16, 16, 2), 256, 0, stream>>>(qkvb, vtb, so);
  state_kernel<<<dim3(64, 15), 256, 0, stream>>>(qkvb, kn, ret, co, Sbuf);
  combine_kernel<<<512, 256, 0, stream>>>(Sbuf, ret64, Fs);
  scan_out_kernel<<<dim3(64, 16), 256, 0, stream>>>(qkvb, kn, W_LTM, ret, co, Fs, stp);
  mix_kernel<<<2048, 256, 0, stream>>>(so, stp, g, mixb);
  gemm_bt_kernel<float><<<dim3(8, 16), 256, 0, stream>>>(mixb, wot, out, 2048, 1024, 1024);
}